// Round 2
// baseline (4237.545 us; speedup 1.0000x reference)
//
#include <hip/hip_runtime.h>
#include <hip/hip_bf16.h>
#include <stdint.h>

#define BATCH 8
#define NTOK 4096
#define DIM 640
#define SEG 128
#define NHEADS 8
#define CH 64
#define SCALE_F 0.11180339887498948f
#define EPS_F 1e-5f
#define BNSCALE 0.99999500003749972f

typedef unsigned short u16;

__device__ __forceinline__ float b2f(u16 u){
  union { float f; unsigned int i; } c; c.i = ((unsigned int)u)<<16; return c.f;
}
__device__ __forceinline__ u16 f2b(float f){
  union { float f; unsigned int i; } c; c.f = f;
  unsigned int i = c.i;
  return (u16)((i + 0x7fffu + ((i>>16)&1u)) >> 16);
}
__device__ __forceinline__ float hswish(float v){
  return v * fminf(fmaxf(v+3.f,0.f),6.f) * (1.f/6.f);
}
__device__ __forceinline__ void unpack8(uint4 pk, float* dst){
  dst[0]=b2f((u16)(pk.x&0xffffu)); dst[1]=b2f((u16)(pk.x>>16));
  dst[2]=b2f((u16)(pk.y&0xffffu)); dst[3]=b2f((u16)(pk.y>>16));
  dst[4]=b2f((u16)(pk.z&0xffffu)); dst[5]=b2f((u16)(pk.z>>16));
  dst[6]=b2f((u16)(pk.w&0xffffu)); dst[7]=b2f((u16)(pk.w>>16));
}
// load 8 consecutive elements starting at element index idx into fp32 dst
template<bool F32>
__device__ __forceinline__ void ld8(const void* base, size_t idx, float* dst){
  if constexpr (F32){
    const float* p = (const float*)base + idx;
    float4 a = *(const float4*)p; float4 b = *(const float4*)(p+4);
    dst[0]=a.x;dst[1]=a.y;dst[2]=a.z;dst[3]=a.w;dst[4]=b.x;dst[5]=b.y;dst[6]=b.z;dst[7]=b.w;
  } else {
    uint4 pk = *(const uint4*)((const u16*)base + idx);
    unpack8(pk,dst);
  }
}

// C[r,o] = sum_k A[r,k]*Wt[o,k]; 64x64 tile, K-chunk 32, fp32 acc.
// MODE 0: scatter bf16 to kvbuf (2,B,N,DIM). MODE 1: +bias, fp32 row-major out (M x 640).
// MODE 2: BN+hswish -> bf16 head tensor (b_,8,N,64) at headbase.
template<int MODE, bool AF32, bool WF32>
__global__ __launch_bounds__(256)
void gemm_bt(const void* __restrict__ A, const void* __restrict__ Wt,
             const float* __restrict__ e1, const float* __restrict__ e2,
             void* __restrict__ out, int K, int headbase)
{
  __shared__ float As[64][36];
  __shared__ float Bs[64][36];
  int tid = threadIdx.x;
  int rb = blockIdx.x*64, cb = blockIdx.y*64;
  int lr = tid>>2, lk = (tid&3)*8;
  int ty = tid>>4, tx = tid&15;
  float acc[4][4] = {};
  for (int k0=0;k0<K;k0+=32){
    float fa[8], fb[8];
    ld8<AF32>(A, (size_t)(rb+lr)*K + k0 + lk, fa);
    ld8<WF32>(Wt, (size_t)(cb+lr)*K + k0 + lk, fb);
    #pragma unroll
    for (int u=0;u<8;u++){ As[lr][lk+u]=fa[u]; Bs[lr][lk+u]=fb[u]; }
    __syncthreads();
    #pragma unroll
    for (int kk=0;kk<32;kk+=4){
      float4 av[4], wv[4];
      #pragma unroll
      for (int i=0;i<4;i++) av[i] = *(const float4*)&As[ty*4+i][kk];
      #pragma unroll
      for (int j=0;j<4;j++) wv[j] = *(const float4*)&Bs[tx*4+j][kk];
      #pragma unroll
      for (int i=0;i<4;i++)
        #pragma unroll
        for (int j=0;j<4;j++)
          acc[i][j] += av[i].x*wv[j].x + av[i].y*wv[j].y + av[i].z*wv[j].z + av[i].w*wv[j].w;
    }
    __syncthreads();
  }
  #pragma unroll
  for (int i=0;i<4;i++){
    int r = rb + ty*4 + i;
    int bb = r>>12, n = r&4095;
    #pragma unroll
    for (int j=0;j<4;j++){
      int o = cb + tx*4 + j;
      float v = acc[i][j];
      if (MODE==0){
        int s = (o>=DIM)?1:0; int co = o - s*DIM;
        ((u16*)out)[(((size_t)(s*BATCH+bb))*NTOK + n)*DIM + co] = f2b(v);
      } else if (MODE==1){
        ((float*)out)[(size_t)r*DIM + o] = v + e1[o];
      } else {
        float val = hswish(v * (e1[o]*BNSCALE) + e2[o]);
        int head = headbase + (o>>6), c = o&63;
        ((u16*)out)[(((size_t)bb*NHEADS + head)*NTOK + n)*CH + c] = f2b(val);
      }
    }
  }
}

// branch 0: no conv, BN+hswish straight into heads 0,1
template<bool INF32>
__global__ void x0_k(const void* __restrict__ in, const float* __restrict__ g,
                     const float* __restrict__ b, u16* __restrict__ hout, int total)
{
  int idx = blockIdx.x*256 + threadIdx.x;
  if (idx>=total) return;
  int c = idx&127; int n = (idx>>7)&4095; int bb = idx>>19;
  size_t ofs = ((size_t)bb*NTOK+n)*DIM + c;
  float xv = INF32 ? ((const float*)in)[ofs] : b2f(((const u16*)in)[ofs]);
  float v = xv * (g[c]*BNSCALE) + b[c];
  v = hswish(v);
  int head = c>>6, ch = c&63;
  hout[(((size_t)bb*NHEADS+head)*NTOK+n)*CH+ch] = f2b(v);
}

// depthwise conv over one 128-ch segment of a (b_,N,640) tensor -> (b_,N,128) bf16
template<bool INF32>
__global__ void dwconv_k(const void* __restrict__ in, int segoff, const float* __restrict__ w,
                         int T, u16* __restrict__ out, int total)
{
  int idx = blockIdx.x*256 + threadIdx.x;
  if (idx>=total) return;
  int c = idx&127; int n = (idx>>7)&4095; int bb = idx>>19;
  int yy = n>>6, xx = n&63;
  int P = T>>1;
  const float* wp = w + c*T*T;
  size_t basein = (size_t)bb*NTOK*DIM + segoff + c;
  float acc = 0.f;
  for (int dy=0;dy<T;dy++){
    int y2 = yy+dy-P; if ((unsigned)y2>=64u) continue;
    for (int dx=0;dx<T;dx++){
      int x2 = xx+dx-P; if ((unsigned)x2>=64u) continue;
      size_t ofs = basein + (size_t)(y2*64+x2)*DIM;
      float xv = INF32 ? ((const float*)in)[ofs] : b2f(((const u16*)in)[ofs]);
      acc += wp[dy*T+dx] * xv;
    }
  }
  out[idx] = f2b(acc);
}

// pointwise 128x128 + LayerNorm(128) + hswish -> loc (8,N,128) bf16. 32 rows x 128 cols per block.
__global__ __launch_bounds__(256)
void pconv_ln(const u16* __restrict__ A, const float* __restrict__ W,
              const float* __restrict__ g, const float* __restrict__ bp,
              u16* __restrict__ out)
{
  __shared__ float Wc[128][36];
  __shared__ float Ac[32][36];
  int tid = threadIdx.x;
  int r0 = blockIdx.x*32;
  int ty = tid>>5, tx = tid&31;
  float acc[4][4] = {};
  for (int k0=0;k0<128;k0+=32){
    {
      int row = tid>>1, kk = (tid&1)*16;
      const float* wr = W + (size_t)row*128 + k0 + kk;
      float4 a0=*(const float4*)wr, a1=*(const float4*)(wr+4);
      float4 a2=*(const float4*)(wr+8), a3=*(const float4*)(wr+12);
      Wc[row][kk+0]=a0.x; Wc[row][kk+1]=a0.y; Wc[row][kk+2]=a0.z; Wc[row][kk+3]=a0.w;
      Wc[row][kk+4]=a1.x; Wc[row][kk+5]=a1.y; Wc[row][kk+6]=a1.z; Wc[row][kk+7]=a1.w;
      Wc[row][kk+8]=a2.x; Wc[row][kk+9]=a2.y; Wc[row][kk+10]=a2.z; Wc[row][kk+11]=a2.w;
      Wc[row][kk+12]=a3.x; Wc[row][kk+13]=a3.y; Wc[row][kk+14]=a3.z; Wc[row][kk+15]=a3.w;
    }
    {
      int row = tid>>3, kk = (tid&7)*4;
      uint2 p = *(const uint2*)(A + (size_t)(r0+row)*128 + k0 + kk);
      Ac[row][kk+0]=b2f((u16)(p.x&0xffffu)); Ac[row][kk+1]=b2f((u16)(p.x>>16));
      Ac[row][kk+2]=b2f((u16)(p.y&0xffffu)); Ac[row][kk+3]=b2f((u16)(p.y>>16));
    }
    __syncthreads();
    #pragma unroll
    for (int kk=0;kk<32;kk+=4){
      float4 av[4], wv[4];
      #pragma unroll
      for (int i=0;i<4;i++) av[i] = *(const float4*)&Ac[ty*4+i][kk];
      #pragma unroll
      for (int j=0;j<4;j++) wv[j] = *(const float4*)&Wc[tx*4+j][kk];
      #pragma unroll
      for (int i=0;i<4;i++)
        #pragma unroll
        for (int j=0;j<4;j++)
          acc[i][j] += av[i].x*wv[j].x + av[i].y*wv[j].y + av[i].z*wv[j].z + av[i].w*wv[j].w;
    }
    __syncthreads();
  }
  #pragma unroll
  for (int i=0;i<4;i++){
    float s1=0.f,s2=0.f;
    #pragma unroll
    for (int j=0;j<4;j++){ s1+=acc[i][j]; s2+=acc[i][j]*acc[i][j]; }
    for (int m=1;m<32;m<<=1){ s1 += __shfl_xor(s1,m,32); s2 += __shfl_xor(s2,m,32); }
    float mean = s1*(1.f/128.f);
    float var = s2*(1.f/128.f) - mean*mean;
    float rstd = 1.f/sqrtf(var + EPS_F);
    int r = r0 + ty*4 + i; int bb = r>>12; int n = r&4095;
    #pragma unroll
    for (int j=0;j<4;j++){
      int c = tx*4+j;
      float val = (acc[i][j]-mean)*rstd*g[c] + bp[c];
      out[((size_t)bb*NTOK+n)*SEG + c] = f2b(hswish(val));
    }
  }
}

__global__ __launch_bounds__(1024)
void softmax_stats(const u16* __restrict__ kh, float* __restrict__ m, float* __restrict__ s)
{
  __shared__ float redm[16][64];
  __shared__ float reds[16][64];
  int bh = blockIdx.x;
  const u16* kp = kh + (size_t)bh*NTOK*CH;
  int ch = threadIdx.x&63, str = threadIdx.x>>6;
  float mx = -1e30f;
  for (int i=0;i<256;i++){
    int n = str*256+i;
    mx = fmaxf(mx, b2f(kp[(size_t)n*CH+ch]));
  }
  redm[str][ch]=mx;
  __syncthreads();
  if (str==0){
    for (int i=1;i<16;i++) mx=fmaxf(mx,redm[i][ch]);
    redm[0][ch]=mx;
  }
  __syncthreads();
  mx = redm[0][ch];
  float sm=0.f;
  for (int i=0;i<256;i++){
    int n = str*256+i;
    sm += expf(b2f(kp[(size_t)n*CH+ch]) - mx);
  }
  reds[str][ch]=sm;
  __syncthreads();
  if (str==0){
    for (int i=1;i<16;i++) sm+=reds[i][ch];
    m[bh*CH+ch]=mx; s[bh*CH+ch]=sm;
  }
}

__global__ __launch_bounds__(256)
void ktv_partial(const u16* __restrict__ kh, const u16* __restrict__ vh,
                 const float* __restrict__ m, float* __restrict__ part)
{
  __shared__ float ek[8][64];
  __shared__ float vv[8][64];
  __shared__ float msh[64];
  int bh = blockIdx.y, chunk = blockIdx.x;
  int tid = threadIdx.x;
  const u16* kp = kh + ((size_t)bh*NTOK + chunk*256)*CH;
  const u16* vp = vh + ((size_t)bh*NTOK + chunk*256)*CH;
  if (tid<64) msh[tid]=m[bh*CH+tid];
  __syncthreads();
  int tkc = tid>>4, tvc = tid&15;
  float acc[4][4]={};
  for (int nn=0;nn<256;nn+=8){
    for (int e=tid;e<512;e+=256){
      int r=e>>6, c=e&63;
      ek[r][c]=expf(b2f(kp[(size_t)(nn+r)*CH+c]) - msh[c]);
      vv[r][c]=b2f(vp[(size_t)(nn+r)*CH+c]);
    }
    __syncthreads();
    #pragma unroll
    for (int i=0;i<8;i++){
      float a[4],b[4];
      #pragma unroll
      for(int u=0;u<4;u++) a[u]=ek[i][tkc*4+u];
      #pragma unroll
      for(int u=0;u<4;u++) b[u]=vv[i][tvc*4+u];
      #pragma unroll
      for(int u=0;u<4;u++)
        #pragma unroll
        for(int w=0;w<4;w++) acc[u][w]+=a[u]*b[w];
    }
    __syncthreads();
  }
  float* pp = part + (((size_t)bh*16 + chunk)*CH*CH);
  #pragma unroll
  for(int u=0;u<4;u++)
    #pragma unroll
    for(int w=0;w<4;w++)
      pp[(tkc*4+u)*CH + tvc*4+w] = acc[u][w];
}

__global__ void ktv_reduce(const float* __restrict__ part, const float* __restrict__ s,
                           float* __restrict__ ktv)
{
  int bh = blockIdx.x; int tid = threadIdx.x;
  for (int o=tid;o<CH*CH;o+=256){
    float sum=0.f;
    for (int c=0;c<16;c++) sum += part[(((size_t)bh*16+c)*CH*CH)+o];
    ktv[(size_t)bh*CH*CH+o] = sum / s[bh*CH + (o>>6)];
  }
}

__global__ void crpe_k(const u16* __restrict__ vh, const float* __restrict__ w3,
                       const float* __restrict__ w5, const float* __restrict__ w7,
                       u16* __restrict__ cbuf)
{
  int bh = blockIdx.y; int h = bh&7;
  int tid = threadIdx.x;
  int ch = tid&63; int px = tid>>6;
  int n = blockIdx.x*4 + px;
  int yy = n>>6, xx = n&63;
  const u16* vp = vh + ((size_t)bh*NTOK)*CH + ch;
  int T; const float* wp;
  if (h<2){ T=3; wp = w3 + (h*64+ch)*9; }
  else if (h<5){ T=5; wp = w5 + ((h-2)*64+ch)*25; }
  else { T=7; wp = w7 + ((h-5)*64+ch)*49; }
  int P=T>>1;
  float acc=0.f;
  for (int dy=0;dy<T;dy++){
    int y2=yy+dy-P; if((unsigned)y2>=64u) continue;
    for (int dx=0;dx<T;dx++){
      int x2=xx+dx-P; if((unsigned)x2>=64u) continue;
      acc += wp[dy*T+dx] * b2f(vp[(size_t)(y2*64+x2)*CH]);
    }
  }
  cbuf[((size_t)bh*NTOK+n)*CH+ch] = f2b(acc);
}

__global__ __launch_bounds__(256)
void oassm_k(const u16* __restrict__ qh, const float* __restrict__ ktv,
             const u16* __restrict__ cbuf, u16* __restrict__ obuf)
{
  __shared__ float kt[64][65];
  __shared__ u16 qs[64][64];
  int bh = blockIdx.y; int b=bh>>3, h=bh&7;
  int n0 = blockIdx.x*64;
  int tid = threadIdx.x;
  const float* kp = ktv + (size_t)bh*CH*CH;
  for (int e=tid;e<4096;e+=256) kt[e>>6][e&63]=kp[e];
  const u16* qp = qh + ((size_t)bh*NTOK + n0)*CH;
  for (int e=tid;e<4096;e+=256) qs[e>>6][e&63]=qp[e];
  __syncthreads();
  int tn=tid>>4, tv=tid&15;
  float eff[4][4]={};
  for (int kc=0;kc<64;kc++){
    float a[4],w[4];
    #pragma unroll
    for(int i=0;i<4;i++) a[i]=b2f(qs[tn*4+i][kc]);
    #pragma unroll
    for(int j=0;j<4;j++) w[j]=kt[kc][tv*4+j];
    #pragma unroll
    for(int i=0;i<4;i++)
      #pragma unroll
      for(int j=0;j<4;j++) eff[i][j]+=a[i]*w[j];
  }
  #pragma unroll
  for (int i=0;i<4;i++){
    int n=n0+tn*4+i;
    const u16* cp = cbuf + ((size_t)bh*NTOK+n)*CH;
    u16* op = obuf + ((size_t)b*NTOK+n)*DIM + h*CH;
    #pragma unroll
    for (int j=0;j<4;j++){
      int vc=tv*4+j;
      float val = SCALE_F*eff[i][j] + b2f(qs[tn*4+i][vc])*b2f(cp[vc]);
      op[vc]=f2b(val);
    }
  }
}

__global__ void loccat_k(const u16* __restrict__ l1, const u16* __restrict__ l2,
                         u16* __restrict__ obuf)
{
  int idx = blockIdx.x*256+threadIdx.x;
  int j = idx&127; int n=(idx>>7)&4095; int bb=idx>>19;
  obuf[((size_t)bb*NTOK+n)*DIM + 512 + j] = f2b(b2f(l1[idx]) + b2f(l2[idx]));
}

extern "C" void kernel_launch(void* const* d_in, const int* in_sizes, int n_in,
                              void* d_out, int out_size, void* d_ws, size_t ws_size,
                              hipStream_t stream)
{
  const float* x = (const float*)d_in[0];
  const float* y = (const float*)d_in[1];
  const float* kv_w = (const float*)d_in[2];
  const float* proj_w = (const float*)d_in[3];
  const float* proj_b = (const float*)d_in[4];
  const float* crpe_w3 = (const float*)d_in[5];
  const float* crpe_w5 = (const float*)d_in[6];
  const float* crpe_w7 = (const float*)d_in[7];
  const float* aq_dw3 = (const float*)d_in[8];
  const float* aq_dw5 = (const float*)d_in[9];
  const float* aq_dw7 = (const float*)d_in[10];
  const float* aq_pw  = (const float*)d_in[11];
  const float* aq_ln_g = (const float*)d_in[12];
  const float* aq_ln_b = (const float*)d_in[13];
  const float* aq_bn_g = (const float*)d_in[14];
  const float* aq_bn_b = (const float*)d_in[15];
  const float* akv_dw3 = (const float*)d_in[16];
  const float* akv_dw5 = (const float*)d_in[17];
  const float* akv_dw7 = (const float*)d_in[18];
  const float* akv_pw  = (const float*)d_in[19];
  const float* akv_ln_g = (const float*)d_in[20];
  const float* akv_ln_b = (const float*)d_in[21];
  const float* akv_bn_g = (const float*)d_in[22];
  const float* akv_bn_b = (const float*)d_in[23];

  char* ws = (char*)d_ws;
  size_t off=0;
  auto alloc=[&](size_t bytes)->char*{ char* p = ws+off; off=(off+bytes+255)&~(size_t)255; return p; };
  u16* kvbuf = (u16*)alloc((size_t)16*NTOK*DIM*2);
  u16* kvh   = (u16*)alloc((size_t)16*NHEADS*NTOK*CH*2);
  u16* qh    = (u16*)alloc((size_t)8*NHEADS*NTOK*CH*2);
  u16* dwbuf = (u16*)alloc((size_t)16*NTOK*SEG*2);
  u16* kvloc = (u16*)alloc((size_t)8*NTOK*SEG*2);
  u16* qloc  = (u16*)alloc((size_t)8*NTOK*SEG*2);
  float* mbuf = (float*)alloc((size_t)64*64*4);
  float* sbuf = (float*)alloc((size_t)64*64*4);
  float* part = (float*)alloc((size_t)64*16*64*64*4);
  float* ktv  = (float*)alloc((size_t)64*64*64*4);
  u16* cbuf  = (u16*)alloc((size_t)64*NTOK*CH*2);
  u16* obuf  = kvbuf; // kvbuf dead once aggregators are done

  // 1. kv projection GEMM: (32768,640) x (1280,640)^T -> scatter bf16 (2,B,N,640)
  gemm_bt<0,true,true><<<dim3(512,20),256,0,stream>>>(x, kv_w, nullptr, nullptr, kvbuf, DIM, 0);

  // 2. kv aggregator (B_=16)
  {
    int tot = 16*NTOK*SEG;
    x0_k<false><<<tot/256,256,0,stream>>>(kvbuf, akv_bn_g, akv_bn_b, kvh, tot);
    dwconv_k<false><<<tot/256,256,0,stream>>>(kvbuf, 128, akv_dw3+1152, 3, dwbuf, tot);
    gemm_bt<2,false,true><<<dim3(16*NTOK/64,2),256,0,stream>>>(dwbuf, akv_pw+1*16384, akv_bn_g+128, akv_bn_b+128, kvh, 128, 2);
    dwconv_k<false><<<tot/256,256,0,stream>>>(kvbuf, 256, akv_dw5, 5, dwbuf, tot);
    gemm_bt<2,false,true><<<dim3(16*NTOK/64,2),256,0,stream>>>(dwbuf, akv_pw+2*16384, akv_bn_g+256, akv_bn_b+256, kvh, 128, 4);
    dwconv_k<false><<<tot/256,256,0,stream>>>(kvbuf, 384, akv_dw7, 7, dwbuf, tot);
    gemm_bt<2,false,true><<<dim3(16*NTOK/64,2),256,0,stream>>>(dwbuf, akv_pw+3*16384, akv_bn_g+384, akv_bn_b+384, kvh, 128, 6);
    int tot8 = 8*NTOK*SEG;
    dwconv_k<false><<<tot8/256,256,0,stream>>>(kvbuf + (size_t)8*NTOK*DIM, 512, akv_dw3, 3, dwbuf, tot8);
    pconv_ln<<<8*NTOK/32,256,0,stream>>>(dwbuf, akv_pw, akv_ln_g, akv_ln_b, kvloc);
  }
  // 3. q aggregator (B_=8), input y (fp32) directly
  {
    int tot = 8*NTOK*SEG;
    x0_k<true><<<tot/256,256,0,stream>>>(y, aq_bn_g, aq_bn_b, qh, tot);
    dwconv_k<true><<<tot/256,256,0,stream>>>(y, 128, aq_dw3+1152, 3, dwbuf, tot);
    gemm_bt<2,false,true><<<dim3(8*NTOK/64,2),256,0,stream>>>(dwbuf, aq_pw+1*16384, aq_bn_g+128, aq_bn_b+128, qh, 128, 2);
    dwconv_k<true><<<tot/256,256,0,stream>>>(y, 256, aq_dw5, 5, dwbuf, tot);
    gemm_bt<2,false,true><<<dim3(8*NTOK/64,2),256,0,stream>>>(dwbuf, aq_pw+2*16384, aq_bn_g+256, aq_bn_b+256, qh, 128, 4);
    dwconv_k<true><<<tot/256,256,0,stream>>>(y, 384, aq_dw7, 7, dwbuf, tot);
    gemm_bt<2,false,true><<<dim3(8*NTOK/64,2),256,0,stream>>>(dwbuf, aq_pw+3*16384, aq_bn_g+384, aq_bn_b+384, qh, 128, 6);
    dwconv_k<true><<<tot/256,256,0,stream>>>(y, 512, aq_dw3, 3, dwbuf, tot);
    pconv_ln<<<8*NTOK/32,256,0,stream>>>(dwbuf, aq_pw, aq_ln_g, aq_ln_b, qloc);
  }
  const u16* vh = kvh + (size_t)8*NHEADS*NTOK*CH;
  // 4. softmax stats over tokens on k
  softmax_stats<<<64,1024,0,stream>>>(kvh, mbuf, sbuf);
  // 5. kTv = softmax(k)^T v  (per b,h: 64x4096 * 4096x64)
  ktv_partial<<<dim3(16,64),256,0,stream>>>(kvh, vh, mbuf, part);
  ktv_reduce<<<64,256,0,stream>>>(part, sbuf, ktv);
  // 6. CRPE depthwise conv on v
  crpe_k<<<dim3(1024,64),256,0,stream>>>(vh, crpe_w3, crpe_w5, crpe_w7, cbuf);
  // 7. o = SCALE*qh*kTv + qh.*conv(v); concat loc
  oassm_k<<<dim3(64,64),256,0,stream>>>(qh, ktv, cbuf, obuf);
  loccat_k<<<8*NTOK*SEG/256,256,0,stream>>>(kvloc, qloc, obuf);
  // 8. output projection -> fp32 d_out
  gemm_bt<1,false,true><<<dim3(512,10),256,0,stream>>>(obuf, proj_w, proj_b, nullptr, (float*)d_out, DIM, 0);
}

// Round 3
// 2385.587 us; speedup vs baseline: 1.7763x; 1.7763x over previous
//
#include <hip/hip_runtime.h>
#include <hip/hip_bf16.h>
#include <stdint.h>

#define BATCH 8
#define NTOK 4096
#define DIM 640
#define SEG 128
#define NHEADS 8
#define CH 64
#define SCALE_F 0.11180339887498948f
#define EPS_F 1e-5f
#define BNSCALE 0.99999500003749972f

typedef unsigned short u16;
typedef float f32x4 __attribute__((ext_vector_type(4)));
typedef short bf16x8 __attribute__((ext_vector_type(8)));

__device__ __forceinline__ float b2f(u16 u){
  union { float f; unsigned int i; } c; c.i = ((unsigned int)u)<<16; return c.f;
}
__device__ __forceinline__ u16 f2b(float f){
  union { float f; unsigned int i; } c; c.f = f;
  unsigned int i = c.i;
  return (u16)((i + 0x7fffu + ((i>>16)&1u)) >> 16);
}
__device__ __forceinline__ float hswish(float v){
  return v * fminf(fmaxf(v+3.f,0.f),6.f) * (1.f/6.f);
}

// ---------------- fp32 -> bf16 conversion ----------------
__global__ void cvt_k(const float* __restrict__ in, u16* __restrict__ out, int n){
  int idx = (blockIdx.x*256 + threadIdx.x)*4;
  if (idx>=n) return;
  float4 v = *(const float4*)(in+idx);
  ushort4 o;
  o.x=f2b(v.x); o.y=f2b(v.y); o.z=f2b(v.z); o.w=f2b(v.w);
  *(ushort4*)(out+idx) = o;
}

// ---------------- MFMA GEMM ----------------
// C[r,o] = sum_k A[r,k]*Wt[o,k], A (M,K) bf16 row-major, Wt (N,K) bf16 row-major.
// 128x128 tile, BK=64, 4 waves each 64x64.
// MODE 0: scatter bf16 to kvbuf (2,B,N,DIM). MODE 1: +bias -> fp32 (M,640).
// MODE 2: BN+hswish -> bf16 head tensor (b_,8,N,64) at headbase.
template<int MODE>
__global__ __launch_bounds__(256)
void mgemm(const u16* __restrict__ A, const u16* __restrict__ Wt,
           const float* __restrict__ e1, const float* __restrict__ e2,
           void* __restrict__ out, int K, int headbase)
{
  __shared__ u16 As[128*64];
  __shared__ u16 Bs[128*64];
  int tid = threadIdx.x;
  int wid = tid>>6, lane = tid&63;
  int rb = blockIdx.x*128, cb = blockIdx.y*128;
  int wr = wid>>1, wc = wid&1;           // wave quadrant (2x2 of 64x64)
  f32x4 acc[4][4];
  #pragma unroll
  for (int m=0;m<4;m++)
    #pragma unroll
    for (int n=0;n<4;n++) acc[m][n] = (f32x4){0.f,0.f,0.f,0.f};

  const u16* Ab = A + (size_t)rb*K;
  const u16* Bb = Wt + (size_t)cb*K;
  int srow = wid*32 + (lane>>3);         // staging row within tile (this wave: 32 rows)
  int scol = (lane&7)*8;                 // staging k-offset (8 bf16 = 16B)

  for (int k0=0;k0<K;k0+=64){
    // stage A[128][64] and B[128][64]: per wave 4 issues each, 8 rows/issue
    #pragma unroll
    for (int i=0;i<4;i++){
      const u16* sa = Ab + (size_t)(srow + i*8)*K + k0 + scol;
      const u16* sb = Bb + (size_t)(srow + i*8)*K + k0 + scol;
      u16* la = As + (wid*32 + i*8)*64;  // wave-uniform LDS base; HW adds lane*16B
      u16* lb = Bs + (wid*32 + i*8)*64;
      __builtin_amdgcn_global_load_lds((const __attribute__((address_space(1))) void*)sa,
                                       (__attribute__((address_space(3))) void*)la, 16, 0, 0);
      __builtin_amdgcn_global_load_lds((const __attribute__((address_space(1))) void*)sb,
                                       (__attribute__((address_space(3))) void*)lb, 16, 0, 0);
    }
    __syncthreads();
    int fr = lane&15, fk = (lane>>4)*8;
    #pragma unroll
    for (int kk=0;kk<64;kk+=32){
      bf16x8 af[4], bfr[4];
      #pragma unroll
      for (int m=0;m<4;m++) af[m] = *(const bf16x8*)&As[(wr*64 + m*16 + fr)*64 + kk + fk];
      #pragma unroll
      for (int n=0;n<4;n++) bfr[n] = *(const bf16x8*)&Bs[(wc*64 + n*16 + fr)*64 + kk + fk];
      #pragma unroll
      for (int m=0;m<4;m++)
        #pragma unroll
        for (int n=0;n<4;n++)
          acc[m][n] = __builtin_amdgcn_mfma_f32_16x16x32_bf16(af[m], bfr[n], acc[m][n], 0, 0, 0);
    }
    __syncthreads();
  }

  int fr = lane&15, fq = lane>>4;
  #pragma unroll
  for (int m=0;m<4;m++){
    #pragma unroll
    for (int j=0;j<4;j++){
      int r = rb + wr*64 + m*16 + fq*4 + j;
      int bb = r>>12, ntk = r&4095;
      #pragma unroll
      for (int n=0;n<4;n++){
        int o = cb + wc*64 + n*16 + fr;
        float v = acc[m][n][j];
        if (MODE==0){
          int s = (o>=DIM)?1:0; int co = o - s*DIM;
          ((u16*)out)[(((size_t)(s*BATCH+bb))*NTOK + ntk)*DIM + co] = f2b(v);
        } else if (MODE==1){
          ((float*)out)[(size_t)r*DIM + o] = v + e1[o];
        } else {
          float val = hswish(v * (e1[o]*BNSCALE) + e2[o]);
          int head = headbase + (o>>6), c = o&63;
          ((u16*)out)[(((size_t)bb*NHEADS + head)*NTOK + ntk)*CH + c] = f2b(val);
        }
      }
    }
  }
}

// branch 0: no conv, BN+hswish straight into heads 0,1
template<bool INF32>
__global__ void x0_k(const void* __restrict__ in, const float* __restrict__ g,
                     const float* __restrict__ b, u16* __restrict__ hout, int total)
{
  int idx = blockIdx.x*256 + threadIdx.x;
  if (idx>=total) return;
  int c = idx&127; int n = (idx>>7)&4095; int bb = idx>>19;
  size_t ofs = ((size_t)bb*NTOK+n)*DIM + c;
  float xv = INF32 ? ((const float*)in)[ofs] : b2f(((const u16*)in)[ofs]);
  float v = xv * (g[c]*BNSCALE) + b[c];
  v = hswish(v);
  int head = c>>6, ch = c&63;
  hout[(((size_t)bb*NHEADS+head)*NTOK+n)*CH+ch] = f2b(v);
}

// depthwise conv over one 128-ch segment of a (b_,N,640) tensor -> (b_,N,128) bf16
template<bool INF32>
__global__ void dwconv_k(const void* __restrict__ in, int segoff, const float* __restrict__ w,
                         int T, u16* __restrict__ out, int total)
{
  int idx = blockIdx.x*256 + threadIdx.x;
  if (idx>=total) return;
  int c = idx&127; int n = (idx>>7)&4095; int bb = idx>>19;
  int yy = n>>6, xx = n&63;
  int P = T>>1;
  const float* wp = w + c*T*T;
  size_t basein = (size_t)bb*NTOK*DIM + segoff + c;
  float acc = 0.f;
  for (int dy=0;dy<T;dy++){
    int y2 = yy+dy-P; if ((unsigned)y2>=64u) continue;
    for (int dx=0;dx<T;dx++){
      int x2 = xx+dx-P; if ((unsigned)x2>=64u) continue;
      size_t ofs = basein + (size_t)(y2*64+x2)*DIM;
      float xv = INF32 ? ((const float*)in)[ofs] : b2f(((const u16*)in)[ofs]);
      acc += wp[dy*T+dx] * xv;
    }
  }
  out[idx] = f2b(acc);
}

// pointwise 128x128 + LayerNorm(128) + hswish -> loc (8,N,128) bf16.
__global__ __launch_bounds__(256)
void pconv_ln(const u16* __restrict__ A, const float* __restrict__ W,
              const float* __restrict__ g, const float* __restrict__ bp,
              u16* __restrict__ out)
{
  __shared__ float Wc[128][36];
  __shared__ float Ac[32][36];
  int tid = threadIdx.x;
  int r0 = blockIdx.x*32;
  int ty = tid>>5, tx = tid&31;
  float acc[4][4] = {};
  for (int k0=0;k0<128;k0+=32){
    {
      int row = tid>>1, kk = (tid&1)*16;
      const float* wr = W + (size_t)row*128 + k0 + kk;
      float4 a0=*(const float4*)wr, a1=*(const float4*)(wr+4);
      float4 a2=*(const float4*)(wr+8), a3=*(const float4*)(wr+12);
      Wc[row][kk+0]=a0.x; Wc[row][kk+1]=a0.y; Wc[row][kk+2]=a0.z; Wc[row][kk+3]=a0.w;
      Wc[row][kk+4]=a1.x; Wc[row][kk+5]=a1.y; Wc[row][kk+6]=a1.z; Wc[row][kk+7]=a1.w;
      Wc[row][kk+8]=a2.x; Wc[row][kk+9]=a2.y; Wc[row][kk+10]=a2.z; Wc[row][kk+11]=a2.w;
      Wc[row][kk+12]=a3.x; Wc[row][kk+13]=a3.y; Wc[row][kk+14]=a3.z; Wc[row][kk+15]=a3.w;
    }
    {
      int row = tid>>3, kk = (tid&7)*4;
      uint2 p = *(const uint2*)(A + (size_t)(r0+row)*128 + k0 + kk);
      Ac[row][kk+0]=b2f((u16)(p.x&0xffffu)); Ac[row][kk+1]=b2f((u16)(p.x>>16));
      Ac[row][kk+2]=b2f((u16)(p.y&0xffffu)); Ac[row][kk+3]=b2f((u16)(p.y>>16));
    }
    __syncthreads();
    #pragma unroll
    for (int kk=0;kk<32;kk+=4){
      float4 av[4], wv[4];
      #pragma unroll
      for (int i=0;i<4;i++) av[i] = *(const float4*)&Ac[ty*4+i][kk];
      #pragma unroll
      for (int j=0;j<4;j++) wv[j] = *(const float4*)&Wc[tx*4+j][kk];
      #pragma unroll
      for (int i=0;i<4;i++)
        #pragma unroll
        for (int j=0;j<4;j++)
          acc[i][j] += av[i].x*wv[j].x + av[i].y*wv[j].y + av[i].z*wv[j].z + av[i].w*wv[j].w;
    }
    __syncthreads();
  }
  #pragma unroll
  for (int i=0;i<4;i++){
    float s1=0.f,s2=0.f;
    #pragma unroll
    for (int j=0;j<4;j++){ s1+=acc[i][j]; s2+=acc[i][j]*acc[i][j]; }
    for (int m=1;m<32;m<<=1){ s1 += __shfl_xor(s1,m,32); s2 += __shfl_xor(s2,m,32); }
    float mean = s1*(1.f/128.f);
    float var = s2*(1.f/128.f) - mean*mean;
    float rstd = 1.f/sqrtf(var + EPS_F);
    int r = r0 + ty*4 + i; int bb = r>>12; int n = r&4095;
    #pragma unroll
    for (int j=0;j<4;j++){
      int c = tx*4+j;
      float val = (acc[i][j]-mean)*rstd*g[c] + bp[c];
      out[((size_t)bb*NTOK+n)*SEG + c] = f2b(hswish(val));
    }
  }
}

__global__ __launch_bounds__(1024)
void softmax_stats(const u16* __restrict__ kh, float* __restrict__ m, float* __restrict__ s)
{
  __shared__ float redm[16][64];
  __shared__ float reds[16][64];
  int bh = blockIdx.x;
  const u16* kp = kh + (size_t)bh*NTOK*CH;
  int ch = threadIdx.x&63, str = threadIdx.x>>6;
  float mx = -1e30f;
  for (int i=0;i<256;i++){
    int n = str*256+i;
    mx = fmaxf(mx, b2f(kp[(size_t)n*CH+ch]));
  }
  redm[str][ch]=mx;
  __syncthreads();
  if (str==0){
    for (int i=1;i<16;i++) mx=fmaxf(mx,redm[i][ch]);
    redm[0][ch]=mx;
  }
  __syncthreads();
  mx = redm[0][ch];
  float sm=0.f;
  for (int i=0;i<256;i++){
    int n = str*256+i;
    sm += expf(b2f(kp[(size_t)n*CH+ch]) - mx);
  }
  reds[str][ch]=sm;
  __syncthreads();
  if (str==0){
    for (int i=1;i<16;i++) sm+=reds[i][ch];
    m[bh*CH+ch]=mx; s[bh*CH+ch]=sm;
  }
}

__global__ __launch_bounds__(256)
void ktv_partial(const u16* __restrict__ kh, const u16* __restrict__ vh,
                 const float* __restrict__ m, float* __restrict__ part)
{
  __shared__ float ek[8][64];
  __shared__ float vv[8][64];
  __shared__ float msh[64];
  int bh = blockIdx.y, chunk = blockIdx.x;
  int tid = threadIdx.x;
  const u16* kp = kh + ((size_t)bh*NTOK + chunk*256)*CH;
  const u16* vp = vh + ((size_t)bh*NTOK + chunk*256)*CH;
  if (tid<64) msh[tid]=m[bh*CH+tid];
  __syncthreads();
  int tkc = tid>>4, tvc = tid&15;
  float acc[4][4]={};
  for (int nn=0;nn<256;nn+=8){
    for (int e=tid;e<512;e+=256){
      int r=e>>6, c=e&63;
      ek[r][c]=expf(b2f(kp[(size_t)(nn+r)*CH+c]) - msh[c]);
      vv[r][c]=b2f(vp[(size_t)(nn+r)*CH+c]);
    }
    __syncthreads();
    #pragma unroll
    for (int i=0;i<8;i++){
      float a[4],b[4];
      #pragma unroll
      for(int u=0;u<4;u++) a[u]=ek[i][tkc*4+u];
      #pragma unroll
      for(int u=0;u<4;u++) b[u]=vv[i][tvc*4+u];
      #pragma unroll
      for(int u=0;u<4;u++)
        #pragma unroll
        for(int w=0;w<4;w++) acc[u][w]+=a[u]*b[w];
    }
    __syncthreads();
  }
  float* pp = part + (((size_t)bh*16 + chunk)*CH*CH);
  #pragma unroll
  for(int u=0;u<4;u++)
    #pragma unroll
    for(int w=0;w<4;w++)
      pp[(tkc*4+u)*CH + tvc*4+w] = acc[u][w];
}

__global__ void ktv_reduce(const float* __restrict__ part, const float* __restrict__ s,
                           float* __restrict__ ktv)
{
  int bh = blockIdx.x; int tid = threadIdx.x;
  for (int o=tid;o<CH*CH;o+=256){
    float sum=0.f;
    for (int c=0;c<16;c++) sum += part[(((size_t)bh*16+c)*CH*CH)+o];
    ktv[(size_t)bh*CH*CH+o] = sum / s[bh*CH + (o>>6)];
  }
}

__global__ void crpe_k(const u16* __restrict__ vh, const float* __restrict__ w3,
                       const float* __restrict__ w5, const float* __restrict__ w7,
                       u16* __restrict__ cbuf)
{
  int bh = blockIdx.y; int h = bh&7;
  int tid = threadIdx.x;
  int ch = tid&63; int px = tid>>6;
  int n = blockIdx.x*4 + px;
  int yy = n>>6, xx = n&63;
  const u16* vp = vh + ((size_t)bh*NTOK)*CH + ch;
  int T; const float* wp;
  if (h<2){ T=3; wp = w3 + (h*64+ch)*9; }
  else if (h<5){ T=5; wp = w5 + ((h-2)*64+ch)*25; }
  else { T=7; wp = w7 + ((h-5)*64+ch)*49; }
  int P=T>>1;
  float acc=0.f;
  for (int dy=0;dy<T;dy++){
    int y2=yy+dy-P; if((unsigned)y2>=64u) continue;
    for (int dx=0;dx<T;dx++){
      int x2=xx+dx-P; if((unsigned)x2>=64u) continue;
      acc += wp[dy*T+dx] * b2f(vp[(size_t)(y2*64+x2)*CH]);
    }
  }
  cbuf[((size_t)bh*NTOK+n)*CH+ch] = f2b(acc);
}

__global__ __launch_bounds__(256)
void oassm_k(const u16* __restrict__ qh, const float* __restrict__ ktv,
             const u16* __restrict__ cbuf, u16* __restrict__ obuf)
{
  __shared__ float kt[64][65];
  __shared__ u16 qs[64][64];
  int bh = blockIdx.y; int b=bh>>3, h=bh&7;
  int n0 = blockIdx.x*64;
  int tid = threadIdx.x;
  const float* kp = ktv + (size_t)bh*CH*CH;
  for (int e=tid;e<4096;e+=256) kt[e>>6][e&63]=kp[e];
  const u16* qp = qh + ((size_t)bh*NTOK + n0)*CH;
  for (int e=tid;e<4096;e+=256) qs[e>>6][e&63]=qp[e];
  __syncthreads();
  int tn=tid>>4, tv=tid&15;
  float eff[4][4]={};
  for (int kc=0;kc<64;kc++){
    float a[4],w[4];
    #pragma unroll
    for(int i=0;i<4;i++) a[i]=b2f(qs[tn*4+i][kc]);
    #pragma unroll
    for(int j=0;j<4;j++) w[j]=kt[kc][tv*4+j];
    #pragma unroll
    for(int i=0;i<4;i++)
      #pragma unroll
      for(int j=0;j<4;j++) eff[i][j]+=a[i]*w[j];
  }
  #pragma unroll
  for (int i=0;i<4;i++){
    int n=n0+tn*4+i;
    const u16* cp = cbuf + ((size_t)bh*NTOK+n)*CH;
    u16* op = obuf + ((size_t)b*NTOK+n)*DIM + h*CH;
    #pragma unroll
    for (int j=0;j<4;j++){
      int vc=tv*4+j;
      float val = SCALE_F*eff[i][j] + b2f(qs[tn*4+i][vc])*b2f(cp[vc]);
      op[vc]=f2b(val);
    }
  }
}

__global__ void loccat_k(const u16* __restrict__ l1, const u16* __restrict__ l2,
                         u16* __restrict__ obuf)
{
  int idx = blockIdx.x*256+threadIdx.x;
  int j = idx&127; int n=(idx>>7)&4095; int bb=idx>>19;
  obuf[((size_t)bb*NTOK+n)*DIM + 512 + j] = f2b(b2f(l1[idx]) + b2f(l2[idx]));
}

extern "C" void kernel_launch(void* const* d_in, const int* in_sizes, int n_in,
                              void* d_out, int out_size, void* d_ws, size_t ws_size,
                              hipStream_t stream)
{
  const float* x = (const float*)d_in[0];
  const float* y = (const float*)d_in[1];
  const float* kv_w = (const float*)d_in[2];
  const float* proj_w = (const float*)d_in[3];
  const float* proj_b = (const float*)d_in[4];
  const float* crpe_w3 = (const float*)d_in[5];
  const float* crpe_w5 = (const float*)d_in[6];
  const float* crpe_w7 = (const float*)d_in[7];
  const float* aq_dw3 = (const float*)d_in[8];
  const float* aq_dw5 = (const float*)d_in[9];
  const float* aq_dw7 = (const float*)d_in[10];
  const float* aq_pw  = (const float*)d_in[11];
  const float* aq_ln_g = (const float*)d_in[12];
  const float* aq_ln_b = (const float*)d_in[13];
  const float* aq_bn_g = (const float*)d_in[14];
  const float* aq_bn_b = (const float*)d_in[15];
  const float* akv_dw3 = (const float*)d_in[16];
  const float* akv_dw5 = (const float*)d_in[17];
  const float* akv_dw7 = (const float*)d_in[18];
  const float* akv_pw  = (const float*)d_in[19];
  const float* akv_ln_g = (const float*)d_in[20];
  const float* akv_ln_b = (const float*)d_in[21];
  const float* akv_bn_g = (const float*)d_in[22];
  const float* akv_bn_b = (const float*)d_in[23];

  char* ws = (char*)d_ws;
  size_t off=0;
  auto alloc=[&](size_t bytes)->char*{ char* p = ws+off; off=(off+bytes+255)&~(size_t)255; return p; };
  u16* kvbuf = (u16*)alloc((size_t)16*NTOK*DIM*2);
  u16* kvh   = (u16*)alloc((size_t)16*NHEADS*NTOK*CH*2);
  u16* qh    = (u16*)alloc((size_t)8*NHEADS*NTOK*CH*2);
  u16* dwbuf = (u16*)alloc((size_t)16*NTOK*SEG*2);
  u16* kvloc = (u16*)alloc((size_t)8*NTOK*SEG*2);
  u16* qloc  = (u16*)alloc((size_t)8*NTOK*SEG*2);
  float* mbuf = (float*)alloc((size_t)64*64*4);
  float* sbuf = (float*)alloc((size_t)64*64*4);
  float* part = (float*)alloc((size_t)64*16*64*64*4);
  float* ktv  = (float*)alloc((size_t)64*64*64*4);
  u16* cbuf  = (u16*)alloc((size_t)64*NTOK*CH*2);
  u16* xb    = (u16*)alloc((size_t)BATCH*NTOK*DIM*2);
  u16* kvwb  = (u16*)alloc((size_t)2*DIM*DIM*2);
  u16* pwb   = (u16*)alloc((size_t)DIM*DIM*2);
  u16* aqpwb = (u16*)alloc((size_t)4*SEG*SEG*2);
  u16* akvpwb= (u16*)alloc((size_t)4*SEG*SEG*2);
  u16* obuf  = kvbuf; // kvbuf dead once aggregators are done

  // 0. fp32 -> bf16 conversions for GEMM operands
  {
    int nx = BATCH*NTOK*DIM;
    cvt_k<<<(nx/4+255)/256,256,0,stream>>>(x, xb, nx);
    int nw = 2*DIM*DIM;
    cvt_k<<<(nw/4+255)/256,256,0,stream>>>(kv_w, kvwb, nw);
    int np = DIM*DIM;
    cvt_k<<<(np/4+255)/256,256,0,stream>>>(proj_w, pwb, np);
    int na = 4*SEG*SEG;
    cvt_k<<<(na/4+255)/256,256,0,stream>>>(aq_pw, aqpwb, na);
    cvt_k<<<(na/4+255)/256,256,0,stream>>>(akv_pw, akvpwb, na);
  }

  // 1. kv projection GEMM: (32768,640) x (1280,640)^T -> scatter bf16 (2,B,N,640)
  mgemm<0><<<dim3(256,10),256,0,stream>>>(xb, kvwb, nullptr, nullptr, kvbuf, DIM, 0);

  // 2. kv aggregator (B_=16)
  {
    int tot = 16*NTOK*SEG;
    x0_k<false><<<tot/256,256,0,stream>>>(kvbuf, akv_bn_g, akv_bn_b, kvh, tot);
    dwconv_k<false><<<tot/256,256,0,stream>>>(kvbuf, 128, akv_dw3+1152, 3, dwbuf, tot);
    mgemm<2><<<dim3(512,1),256,0,stream>>>(dwbuf, akvpwb+1*16384, akv_bn_g+128, akv_bn_b+128, kvh, 128, 2);
    dwconv_k<false><<<tot/256,256,0,stream>>>(kvbuf, 256, akv_dw5, 5, dwbuf, tot);
    mgemm<2><<<dim3(512,1),256,0,stream>>>(dwbuf, akvpwb+2*16384, akv_bn_g+256, akv_bn_b+256, kvh, 128, 4);
    dwconv_k<false><<<tot/256,256,0,stream>>>(kvbuf, 384, akv_dw7, 7, dwbuf, tot);
    mgemm<2><<<dim3(512,1),256,0,stream>>>(dwbuf, akvpwb+3*16384, akv_bn_g+384, akv_bn_b+384, kvh, 128, 6);
    int tot8 = 8*NTOK*SEG;
    dwconv_k<false><<<tot8/256,256,0,stream>>>(kvbuf + (size_t)8*NTOK*DIM, 512, akv_dw3, 3, dwbuf, tot8);
    pconv_ln<<<8*NTOK/32,256,0,stream>>>(dwbuf, akv_pw, akv_ln_g, akv_ln_b, kvloc);
  }
  // 3. q aggregator (B_=8), input y (fp32) directly
  {
    int tot = 8*NTOK*SEG;
    x0_k<true><<<tot/256,256,0,stream>>>(y, aq_bn_g, aq_bn_b, qh, tot);
    dwconv_k<true><<<tot/256,256,0,stream>>>(y, 128, aq_dw3+1152, 3, dwbuf, tot);
    mgemm<2><<<dim3(256,1),256,0,stream>>>(dwbuf, aqpwb+1*16384, aq_bn_g+128, aq_bn_b+128, qh, 128, 2);
    dwconv_k<true><<<tot/256,256,0,stream>>>(y, 256, aq_dw5, 5, dwbuf, tot);
    mgemm<2><<<dim3(256,1),256,0,stream>>>(dwbuf, aqpwb+2*16384, aq_bn_g+256, aq_bn_b+256, qh, 128, 4);
    dwconv_k<true><<<tot/256,256,0,stream>>>(y, 384, aq_dw7, 7, dwbuf, tot);
    mgemm<2><<<dim3(256,1),256,0,stream>>>(dwbuf, aqpwb+3*16384, aq_bn_g+384, aq_bn_b+384, qh, 128, 6);
    dwconv_k<true><<<tot/256,256,0,stream>>>(y, 512, aq_dw3, 3, dwbuf, tot);
    pconv_ln<<<8*NTOK/32,256,0,stream>>>(dwbuf, aq_pw, aq_ln_g, aq_ln_b, qloc);
  }
  const u16* vh = kvh + (size_t)8*NHEADS*NTOK*CH;
  // 4. softmax stats over tokens on k
  softmax_stats<<<64,1024,0,stream>>>(kvh, mbuf, sbuf);
  // 5. kTv = softmax(k)^T v  (per b,h: 64x4096 * 4096x64)
  ktv_partial<<<dim3(16,64),256,0,stream>>>(kvh, vh, mbuf, part);
  ktv_reduce<<<64,256,0,stream>>>(part, sbuf, ktv);
  // 6. CRPE depthwise conv on v
  crpe_k<<<dim3(1024,64),256,0,stream>>>(vh, crpe_w3, crpe_w5, crpe_w7, cbuf);
  // 7. o = SCALE*qh*kTv + qh.*conv(v); concat loc
  oassm_k<<<dim3(64,64),256,0,stream>>>(qh, ktv, cbuf, obuf);
  loccat_k<<<8*NTOK*SEG/256,256,0,stream>>>(kvloc, qloc, obuf);
  // 8. output projection -> fp32 d_out
  mgemm<1><<<dim3(256,5),256,0,stream>>>(obuf, pwb, proj_b, nullptr, (float*)d_out, DIM, 0);
}

// Round 4
// 910.357 us; speedup vs baseline: 4.6548x; 2.6205x over previous
//
#include <hip/hip_runtime.h>
#include <hip/hip_bf16.h>
#include <stdint.h>

#define BATCH 8
#define NTOK 4096
#define DIM 640
#define SEG 128
#define NHEADS 8
#define CH 64
#define SCALE_F 0.11180339887498948f
#define EPS_F 1e-5f
#define BNSCALE 0.99999500003749972f

typedef unsigned short u16;
typedef float f32x4 __attribute__((ext_vector_type(4)));
typedef short bf16x8 __attribute__((ext_vector_type(8)));

__device__ __forceinline__ float b2f(u16 u){
  union { float f; unsigned int i; } c; c.i = ((unsigned int)u)<<16; return c.f;
}
__device__ __forceinline__ u16 f2b(float f){
  union { float f; unsigned int i; } c; c.f = f;
  unsigned int i = c.i;
  return (u16)((i + 0x7fffu + ((i>>16)&1u)) >> 16);
}
__device__ __forceinline__ float hswish(float v){
  return v * fminf(fmaxf(v+3.f,0.f),6.f) * (1.f/6.f);
}

// ---------------- fp32 -> bf16 conversion ----------------
__global__ void cvt_k(const float* __restrict__ in, u16* __restrict__ out, int n){
  int idx = (blockIdx.x*256 + threadIdx.x)*4;
  if (idx>=n) return;
  float4 v = *(const float4*)(in+idx);
  ushort4 o;
  o.x=f2b(v.x); o.y=f2b(v.y); o.z=f2b(v.z); o.w=f2b(v.w);
  *(ushort4*)(out+idx) = o;
}

// ---------------- MFMA GEMM ----------------
// C[r,o] = sum_k A[r,k]*Wt[o,k], A (M,K) bf16 row-major, Wt (N,K) bf16 row-major.
// 128x128 tile, BK=64, 4 waves each 64x64.
// MODE 0: scatter bf16 to kvbuf (2,B,N,DIM). MODE 1: +bias -> fp32 (M,640).
// MODE 2: BN+hswish -> bf16 head tensor (b_,8,N,64) at headbase.
template<int MODE>
__global__ __launch_bounds__(256)
void mgemm(const u16* __restrict__ A, const u16* __restrict__ Wt,
           const float* __restrict__ e1, const float* __restrict__ e2,
           void* __restrict__ out, int K, int headbase)
{
  __shared__ u16 As[128*64];
  __shared__ u16 Bs[128*64];
  int tid = threadIdx.x;
  int wid = tid>>6, lane = tid&63;
  int rb = blockIdx.x*128, cb = blockIdx.y*128;
  int wr = wid>>1, wc = wid&1;           // wave quadrant (2x2 of 64x64)
  f32x4 acc[4][4];
  #pragma unroll
  for (int m=0;m<4;m++)
    #pragma unroll
    for (int n=0;n<4;n++) acc[m][n] = (f32x4){0.f,0.f,0.f,0.f};

  const u16* Ab = A + (size_t)rb*K;
  const u16* Bb = Wt + (size_t)cb*K;
  int srow = wid*32 + (lane>>3);         // staging row within tile (this wave: 32 rows)
  int scol = (lane&7)*8;                 // staging k-offset (8 bf16 = 16B)

  for (int k0=0;k0<K;k0+=64){
    #pragma unroll
    for (int i=0;i<4;i++){
      const u16* sa = Ab + (size_t)(srow + i*8)*K + k0 + scol;
      const u16* sb = Bb + (size_t)(srow + i*8)*K + k0 + scol;
      u16* la = As + (wid*32 + i*8)*64;
      u16* lb = Bs + (wid*32 + i*8)*64;
      __builtin_amdgcn_global_load_lds((const __attribute__((address_space(1))) void*)sa,
                                       (__attribute__((address_space(3))) void*)la, 16, 0, 0);
      __builtin_amdgcn_global_load_lds((const __attribute__((address_space(1))) void*)sb,
                                       (__attribute__((address_space(3))) void*)lb, 16, 0, 0);
    }
    __syncthreads();
    int fr = lane&15, fk = (lane>>4)*8;
    #pragma unroll
    for (int kk=0;kk<64;kk+=32){
      bf16x8 af[4], bfr[4];
      #pragma unroll
      for (int m=0;m<4;m++) af[m] = *(const bf16x8*)&As[(wr*64 + m*16 + fr)*64 + kk + fk];
      #pragma unroll
      for (int n=0;n<4;n++) bfr[n] = *(const bf16x8*)&Bs[(wc*64 + n*16 + fr)*64 + kk + fk];
      #pragma unroll
      for (int m=0;m<4;m++)
        #pragma unroll
        for (int n=0;n<4;n++)
          acc[m][n] = __builtin_amdgcn_mfma_f32_16x16x32_bf16(af[m], bfr[n], acc[m][n], 0, 0, 0);
    }
    __syncthreads();
  }

  int fr = lane&15, fq = lane>>4;
  #pragma unroll
  for (int m=0;m<4;m++){
    #pragma unroll
    for (int j=0;j<4;j++){
      int r = rb + wr*64 + m*16 + fq*4 + j;
      int bb = r>>12, ntk = r&4095;
      #pragma unroll
      for (int n=0;n<4;n++){
        int o = cb + wc*64 + n*16 + fr;
        float v = acc[m][n][j];
        if (MODE==0){
          int s = (o>=DIM)?1:0; int co = o - s*DIM;
          ((u16*)out)[(((size_t)(s*BATCH+bb))*NTOK + ntk)*DIM + co] = f2b(v);
        } else if (MODE==1){
          ((float*)out)[(size_t)r*DIM + o] = v + e1[o];
        } else {
          float val = hswish(v * (e1[o]*BNSCALE) + e2[o]);
          int head = headbase + (o>>6), c = o&63;
          ((u16*)out)[(((size_t)bb*NHEADS + head)*NTOK + ntk)*CH + c] = f2b(val);
        }
      }
    }
  }
}

// ---------------- tiled depthwise conv (stencil) ----------------
// 16x16 px tile x 64 channels per block. Input channel-last (PXS elements/px),
// output channel-last bf16 (OPXS elements/px). Halo patch staged in LDS as bf16.
// Image index i = blockIdx.y: i1 = i/NI2, i2 = i%NI2;
// in_off = i1*S1 + i2*S2 (elements), out_off = i1*SO1 + i2*SO2,
// weights: w[(i2*64 + c)*T*T + j], c = lane channel.
template<int T, bool INF32>
__global__ __launch_bounds__(256)
void conv_tile(const void* __restrict__ in, const float* __restrict__ w,
               u16* __restrict__ out, int NI2,
               size_t S1, size_t S2, int PXS,
               size_t SO1, size_t SO2, int OPXS)
{
  constexpr int P = T>>1;
  constexpr int PW = 15 + T;
  __shared__ u16 lds[PW*PW*64];
  int tid = threadIdx.x;
  int tile = blockIdx.x;
  int ty0 = (tile>>2)*16, tx0 = (tile&3)*16;
  int i = blockIdx.y;
  int i1 = i / NI2, i2 = i - i1*NI2;
  size_t in_off = (size_t)i1*S1 + (size_t)i2*S2;
  size_t out_off = (size_t)i1*SO1 + (size_t)i2*SO2;
  int c = tid & 63;

  float wreg[T*T];
  {
    const float* wp = w + (size_t)(i2*64 + c)*(T*T);
    #pragma unroll
    for (int j=0;j<T*T;j++) wreg[j] = wp[j];
  }

  if constexpr (!INF32){
    int l8 = tid&7;
    for (int p = tid>>3; p < PW*PW; p += 32){
      int py = p/PW, pxx = p - py*PW;
      int gy = ty0+py-P, gx = tx0+pxx-P;
      uint4 val = {0u,0u,0u,0u};
      if ((unsigned)gy<64u && (unsigned)gx<64u)
        val = *(const uint4*)((const u16*)in + in_off + (size_t)(gy*64+gx)*PXS + l8*8);
      *(uint4*)&lds[p*64 + l8*8] = val;
    }
  } else {
    int l16 = tid&15;
    for (int p = tid>>4; p < PW*PW; p += 16){
      int py = p/PW, pxx = p - py*PW;
      int gy = ty0+py-P, gx = tx0+pxx-P;
      ushort4 o4 = {0,0,0,0};
      if ((unsigned)gy<64u && (unsigned)gx<64u){
        float4 v = *(const float4*)((const float*)in + in_off + (size_t)(gy*64+gx)*PXS + l16*4);
        o4.x=f2b(v.x); o4.y=f2b(v.y); o4.z=f2b(v.z); o4.w=f2b(v.w);
      }
      *(ushort4*)&lds[p*64 + l16*4] = o4;
    }
  }
  __syncthreads();

  int ox0 = (tid>>6)*4;
  #pragma unroll 1
  for (int r=0;r<16;r++){
    float a0=0.f,a1=0.f,a2=0.f,a3=0.f;
    #pragma unroll
    for (int dy=0;dy<T;dy++){
      const u16* rowp = &lds[((r+dy)*PW + ox0)*64 + c];
      #pragma unroll
      for (int dxx=0;dxx<T+3;dxx++){
        float v = b2f(rowp[dxx*64]);
        if (dxx<T)             a0 += wreg[dy*T+dxx]*v;
        if (dxx>=1 && dxx<T+1) a1 += wreg[dy*T+dxx-1]*v;
        if (dxx>=2 && dxx<T+2) a2 += wreg[dy*T+dxx-2]*v;
        if (dxx>=3)            a3 += wreg[dy*T+dxx-3]*v;
      }
    }
    size_t ob = out_off + (size_t)((ty0+r)*64 + tx0+ox0)*OPXS + c;
    out[ob]          = f2b(a0);
    out[ob +   (size_t)OPXS] = f2b(a1);
    out[ob + 2*(size_t)OPXS] = f2b(a2);
    out[ob + 3*(size_t)OPXS] = f2b(a3);
  }
}

// branch 0: no conv, BN+hswish straight into heads 0,1
template<bool INF32>
__global__ void x0_k(const void* __restrict__ in, const float* __restrict__ g,
                     const float* __restrict__ b, u16* __restrict__ hout, int total)
{
  int idx = blockIdx.x*256 + threadIdx.x;
  if (idx>=total) return;
  int c = idx&127; int n = (idx>>7)&4095; int bb = idx>>19;
  size_t ofs = ((size_t)bb*NTOK+n)*DIM + c;
  float xv = INF32 ? ((const float*)in)[ofs] : b2f(((const u16*)in)[ofs]);
  float v = xv * (g[c]*BNSCALE) + b[c];
  v = hswish(v);
  int head = c>>6, ch = c&63;
  hout[(((size_t)bb*NHEADS+head)*NTOK+n)*CH+ch] = f2b(v);
}

// pointwise 128x128 + LayerNorm(128) + hswish -> loc (8,N,128) bf16.
__global__ __launch_bounds__(256)
void pconv_ln(const u16* __restrict__ A, const float* __restrict__ W,
              const float* __restrict__ g, const float* __restrict__ bp,
              u16* __restrict__ out)
{
  __shared__ float Wc[128][36];
  __shared__ float Ac[32][36];
  int tid = threadIdx.x;
  int r0 = blockIdx.x*32;
  int ty = tid>>5, tx = tid&31;
  float acc[4][4] = {};
  for (int k0=0;k0<128;k0+=32){
    {
      int row = tid>>1, kk = (tid&1)*16;
      const float* wr = W + (size_t)row*128 + k0 + kk;
      float4 a0=*(const float4*)wr, a1=*(const float4*)(wr+4);
      float4 a2=*(const float4*)(wr+8), a3=*(const float4*)(wr+12);
      Wc[row][kk+0]=a0.x; Wc[row][kk+1]=a0.y; Wc[row][kk+2]=a0.z; Wc[row][kk+3]=a0.w;
      Wc[row][kk+4]=a1.x; Wc[row][kk+5]=a1.y; Wc[row][kk+6]=a1.z; Wc[row][kk+7]=a1.w;
      Wc[row][kk+8]=a2.x; Wc[row][kk+9]=a2.y; Wc[row][kk+10]=a2.z; Wc[row][kk+11]=a2.w;
      Wc[row][kk+12]=a3.x; Wc[row][kk+13]=a3.y; Wc[row][kk+14]=a3.z; Wc[row][kk+15]=a3.w;
    }
    {
      int row = tid>>3, kk = (tid&7)*4;
      uint2 p = *(const uint2*)(A + (size_t)(r0+row)*128 + k0 + kk);
      Ac[row][kk+0]=b2f((u16)(p.x&0xffffu)); Ac[row][kk+1]=b2f((u16)(p.x>>16));
      Ac[row][kk+2]=b2f((u16)(p.y&0xffffu)); Ac[row][kk+3]=b2f((u16)(p.y>>16));
    }
    __syncthreads();
    #pragma unroll
    for (int kk=0;kk<32;kk+=4){
      float4 av[4], wv[4];
      #pragma unroll
      for (int i=0;i<4;i++) av[i] = *(const float4*)&Ac[ty*4+i][kk];
      #pragma unroll
      for (int j=0;j<4;j++) wv[j] = *(const float4*)&Wc[tx*4+j][kk];
      #pragma unroll
      for (int i=0;i<4;i++)
        #pragma unroll
        for (int j=0;j<4;j++)
          acc[i][j] += av[i].x*wv[j].x + av[i].y*wv[j].y + av[i].z*wv[j].z + av[i].w*wv[j].w;
    }
    __syncthreads();
  }
  #pragma unroll
  for (int i=0;i<4;i++){
    float s1=0.f,s2=0.f;
    #pragma unroll
    for (int j=0;j<4;j++){ s1+=acc[i][j]; s2+=acc[i][j]*acc[i][j]; }
    for (int m=1;m<32;m<<=1){ s1 += __shfl_xor(s1,m,32); s2 += __shfl_xor(s2,m,32); }
    float mean = s1*(1.f/128.f);
    float var = s2*(1.f/128.f) - mean*mean;
    float rstd = 1.f/sqrtf(var + EPS_F);
    int r = r0 + ty*4 + i; int bb = r>>12; int n = r&4095;
    #pragma unroll
    for (int j=0;j<4;j++){
      int c = tx*4+j;
      float val = (acc[i][j]-mean)*rstd*g[c] + bp[c];
      out[((size_t)bb*NTOK+n)*SEG + c] = f2b(hswish(val));
    }
  }
}

// softmax over tokens: pass1 per-(bh,chunk) max+sumexp, pass2 merge
__global__ __launch_bounds__(256)
void softmax_p1(const u16* __restrict__ kh, float* __restrict__ pm, float* __restrict__ ps)
{
  __shared__ float lm[4][64];
  __shared__ float lsum[4][64];
  int chunk = blockIdx.x, bh = blockIdx.y;
  int tid = threadIdx.x;
  int ch = tid&63, sub = tid>>6;
  const u16* kp = kh + ((size_t)bh*NTOK + chunk*256 + sub*64)*CH + ch;
  float mx = -1e30f;
  for (int t=0;t<64;t++) mx = fmaxf(mx, b2f(kp[(size_t)t*CH]));
  float sm = 0.f;
  for (int t=0;t<64;t++) sm += expf(b2f(kp[(size_t)t*CH]) - mx);
  lm[sub][ch]=mx; lsum[sub][ch]=sm;
  __syncthreads();
  if (sub==0){
    float M = lm[0][ch];
    #pragma unroll
    for (int i=1;i<4;i++) M = fmaxf(M, lm[i][ch]);
    float S = 0.f;
    #pragma unroll
    for (int i=0;i<4;i++) S += lsum[i][ch]*expf(lm[i][ch]-M);
    pm[((size_t)bh*16+chunk)*64+ch]=M;
    ps[((size_t)bh*16+chunk)*64+ch]=S;
  }
}

__global__ void softmax_p2(const float* __restrict__ pm, const float* __restrict__ ps,
                           float* __restrict__ m, float* __restrict__ s)
{
  int bh = blockIdx.x, ch = threadIdx.x;
  float M = -1e30f;
  for (int c=0;c<16;c++) M = fmaxf(M, pm[((size_t)bh*16+c)*64+ch]);
  float S = 0.f;
  for (int c=0;c<16;c++) S += ps[((size_t)bh*16+c)*64+ch]*expf(pm[((size_t)bh*16+c)*64+ch]-M);
  m[bh*CH+ch]=M; s[bh*CH+ch]=S;
}

__global__ __launch_bounds__(256)
void ktv_partial(const u16* __restrict__ kh, const u16* __restrict__ vh,
                 const float* __restrict__ m, float* __restrict__ part)
{
  __shared__ float ek[8][64];
  __shared__ float vv[8][64];
  __shared__ float msh[64];
  int bh = blockIdx.y, chunk = blockIdx.x;
  int tid = threadIdx.x;
  const u16* kp = kh + ((size_t)bh*NTOK + chunk*256)*CH;
  const u16* vp = vh + ((size_t)bh*NTOK + chunk*256)*CH;
  if (tid<64) msh[tid]=m[bh*CH+tid];
  __syncthreads();
  int tkc = tid>>4, tvc = tid&15;
  float acc[4][4]={};
  for (int nn=0;nn<256;nn+=8){
    for (int e=tid;e<512;e+=256){
      int r=e>>6, c=e&63;
      ek[r][c]=expf(b2f(kp[(size_t)(nn+r)*CH+c]) - msh[c]);
      vv[r][c]=b2f(vp[(size_t)(nn+r)*CH+c]);
    }
    __syncthreads();
    #pragma unroll
    for (int i=0;i<8;i++){
      float a[4],b[4];
      #pragma unroll
      for(int u=0;u<4;u++) a[u]=ek[i][tkc*4+u];
      #pragma unroll
      for(int u=0;u<4;u++) b[u]=vv[i][tvc*4+u];
      #pragma unroll
      for(int u=0;u<4;u++)
        #pragma unroll
        for(int w=0;w<4;w++) acc[u][w]+=a[u]*b[w];
    }
    __syncthreads();
  }
  float* pp = part + (((size_t)bh*16 + chunk)*CH*CH);
  #pragma unroll
  for(int u=0;u<4;u++)
    #pragma unroll
    for(int w=0;w<4;w++)
      pp[(tkc*4+u)*CH + tvc*4+w] = acc[u][w];
}

__global__ void ktv_reduce(const float* __restrict__ part, const float* __restrict__ s,
                           float* __restrict__ ktv)
{
  int bh = blockIdx.x; int tid = threadIdx.x;
  for (int o=tid;o<CH*CH;o+=256){
    float sum=0.f;
    for (int c=0;c<16;c++) sum += part[(((size_t)bh*16+c)*CH*CH)+o];
    ktv[(size_t)bh*CH*CH+o] = sum / s[bh*CH + (o>>6)];
  }
}

__global__ __launch_bounds__(256)
void oassm_k(const u16* __restrict__ qh, const float* __restrict__ ktv,
             const u16* __restrict__ cbuf, u16* __restrict__ obuf)
{
  __shared__ float kt[64][65];
  __shared__ u16 qs[64][64];
  int bh = blockIdx.y; int b=bh>>3, h=bh&7;
  int n0 = blockIdx.x*64;
  int tid = threadIdx.x;
  const float* kp = ktv + (size_t)bh*CH*CH;
  for (int e=tid;e<4096;e+=256) kt[e>>6][e&63]=kp[e];
  const u16* qp = qh + ((size_t)bh*NTOK + n0)*CH;
  for (int e=tid;e<4096;e+=256) qs[e>>6][e&63]=qp[e];
  __syncthreads();
  int tn=tid>>4, tv=tid&15;
  float eff[4][4]={};
  for (int kc=0;kc<64;kc++){
    float a[4],w[4];
    #pragma unroll
    for(int i=0;i<4;i++) a[i]=b2f(qs[tn*4+i][kc]);
    #pragma unroll
    for(int j=0;j<4;j++) w[j]=kt[kc][tv*4+j];
    #pragma unroll
    for(int i=0;i<4;i++)
      #pragma unroll
      for(int j=0;j<4;j++) eff[i][j]+=a[i]*w[j];
  }
  #pragma unroll
  for (int i=0;i<4;i++){
    int n=n0+tn*4+i;
    const u16* cp = cbuf + ((size_t)bh*NTOK+n)*CH;
    u16* op = obuf + ((size_t)b*NTOK+n)*DIM + h*CH;
    #pragma unroll
    for (int j=0;j<4;j++){
      int vc=tv*4+j;
      float val = SCALE_F*eff[i][j] + b2f(qs[tn*4+i][vc])*b2f(cp[vc]);
      op[vc]=f2b(val);
    }
  }
}

__global__ void loccat_k(const u16* __restrict__ l1, const u16* __restrict__ l2,
                         u16* __restrict__ obuf)
{
  int idx = blockIdx.x*256+threadIdx.x;
  int j = idx&127; int n=(idx>>7)&4095; int bb=idx>>19;
  obuf[((size_t)bb*NTOK+n)*DIM + 512 + j] = f2b(b2f(l1[idx]) + b2f(l2[idx]));
}

extern "C" void kernel_launch(void* const* d_in, const int* in_sizes, int n_in,
                              void* d_out, int out_size, void* d_ws, size_t ws_size,
                              hipStream_t stream)
{
  const float* x = (const float*)d_in[0];
  const float* y = (const float*)d_in[1];
  const float* kv_w = (const float*)d_in[2];
  const float* proj_w = (const float*)d_in[3];
  const float* proj_b = (const float*)d_in[4];
  const float* crpe_w3 = (const float*)d_in[5];
  const float* crpe_w5 = (const float*)d_in[6];
  const float* crpe_w7 = (const float*)d_in[7];
  const float* aq_dw3 = (const float*)d_in[8];
  const float* aq_dw5 = (const float*)d_in[9];
  const float* aq_dw7 = (const float*)d_in[10];
  const float* aq_pw  = (const float*)d_in[11];
  const float* aq_ln_g = (const float*)d_in[12];
  const float* aq_ln_b = (const float*)d_in[13];
  const float* aq_bn_g = (const float*)d_in[14];
  const float* aq_bn_b = (const float*)d_in[15];
  const float* akv_dw3 = (const float*)d_in[16];
  const float* akv_dw5 = (const float*)d_in[17];
  const float* akv_dw7 = (const float*)d_in[18];
  const float* akv_pw  = (const float*)d_in[19];
  const float* akv_ln_g = (const float*)d_in[20];
  const float* akv_ln_b = (const float*)d_in[21];
  const float* akv_bn_g = (const float*)d_in[22];
  const float* akv_bn_b = (const float*)d_in[23];

  char* ws = (char*)d_ws;
  size_t off=0;
  auto alloc=[&](size_t bytes)->char*{ char* p = ws+off; off=(off+bytes+255)&~(size_t)255; return p; };
  u16* kvbuf = (u16*)alloc((size_t)16*NTOK*DIM*2);
  u16* kvh   = (u16*)alloc((size_t)16*NHEADS*NTOK*CH*2);
  u16* qh    = (u16*)alloc((size_t)8*NHEADS*NTOK*CH*2);
  u16* dwbuf = (u16*)alloc((size_t)16*NTOK*SEG*2);
  u16* kvloc = (u16*)alloc((size_t)8*NTOK*SEG*2);
  u16* qloc  = (u16*)alloc((size_t)8*NTOK*SEG*2);
  float* mbuf = (float*)alloc((size_t)64*64*4);
  float* sbuf = (float*)alloc((size_t)64*64*4);
  float* pmb  = (float*)alloc((size_t)64*16*64*4);
  float* psb  = (float*)alloc((size_t)64*16*64*4);
  float* part = (float*)alloc((size_t)64*16*64*64*4);
  float* ktv  = (float*)alloc((size_t)64*64*64*4);
  u16* cbuf  = (u16*)alloc((size_t)64*NTOK*CH*2);
  u16* xb    = (u16*)alloc((size_t)BATCH*NTOK*DIM*2);
  u16* kvwb  = (u16*)alloc((size_t)2*DIM*DIM*2);
  u16* pwb   = (u16*)alloc((size_t)DIM*DIM*2);
  u16* aqpwb = (u16*)alloc((size_t)4*SEG*SEG*2);
  u16* akvpwb= (u16*)alloc((size_t)4*SEG*SEG*2);
  u16* obuf  = kvbuf; // kvbuf dead once aggregators are done

  const size_t SIMG = (size_t)NTOK*DIM;   // image stride, (b_,N,640)
  const size_t SDW  = (size_t)NTOK*SEG;   // dwbuf image stride
  const size_t SHD  = (size_t)NTOK*CH;    // per-head stride

  // 0. fp32 -> bf16 conversions for GEMM operands
  {
    int nx = BATCH*NTOK*DIM;
    cvt_k<<<(nx/4+255)/256,256,0,stream>>>(x, xb, nx);
    int nw = 2*DIM*DIM;
    cvt_k<<<(nw/4+255)/256,256,0,stream>>>(kv_w, kvwb, nw);
    int np = DIM*DIM;
    cvt_k<<<(np/4+255)/256,256,0,stream>>>(proj_w, pwb, np);
    int na = 4*SEG*SEG;
    cvt_k<<<(na/4+255)/256,256,0,stream>>>(aq_pw, aqpwb, na);
    cvt_k<<<(na/4+255)/256,256,0,stream>>>(akv_pw, akvpwb, na);
  }

  // 1. kv projection GEMM: (32768,640) x (1280,640)^T -> scatter bf16 (2,B,N,640)
  mgemm<0><<<dim3(256,10),256,0,stream>>>(xb, kvwb, nullptr, nullptr, kvbuf, DIM, 0);

  // 2. kv aggregator (B_=16), input kvbuf bf16
  {
    int tot = 16*NTOK*SEG;
    x0_k<false><<<tot/256,256,0,stream>>>(kvbuf, akv_bn_g, akv_bn_b, kvh, tot);
    conv_tile<3,false><<<dim3(16,32),256,0,stream>>>(kvbuf+128, akv_dw3+1152, dwbuf, 2, SIMG, 64, DIM, SDW, 64, SEG);
    mgemm<2><<<dim3(512,1),256,0,stream>>>(dwbuf, akvpwb+1*16384, akv_bn_g+128, akv_bn_b+128, kvh, 128, 2);
    conv_tile<5,false><<<dim3(16,32),256,0,stream>>>(kvbuf+256, akv_dw5, dwbuf, 2, SIMG, 64, DIM, SDW, 64, SEG);
    mgemm<2><<<dim3(512,1),256,0,stream>>>(dwbuf, akvpwb+2*16384, akv_bn_g+256, akv_bn_b+256, kvh, 128, 4);
    conv_tile<7,false><<<dim3(16,32),256,0,stream>>>(kvbuf+384, akv_dw7, dwbuf, 2, SIMG, 64, DIM, SDW, 64, SEG);
    mgemm<2><<<dim3(512,1),256,0,stream>>>(dwbuf, akvpwb+3*16384, akv_bn_g+384, akv_bn_b+384, kvh, 128, 6);
    conv_tile<3,false><<<dim3(16,16),256,0,stream>>>(kvbuf + (size_t)8*SIMG + 512, akv_dw3, dwbuf, 2, SIMG, 64, DIM, SDW, 64, SEG);
    pconv_ln<<<8*NTOK/32,256,0,stream>>>(dwbuf, akv_pw, akv_ln_g, akv_ln_b, kvloc);
  }
  // 3. q aggregator (B_=8), input y fp32
  {
    int tot = 8*NTOK*SEG;
    x0_k<true><<<tot/256,256,0,stream>>>(y, aq_bn_g, aq_bn_b, qh, tot);
    conv_tile<3,true><<<dim3(16,16),256,0,stream>>>(y+128, aq_dw3+1152, dwbuf, 2, SIMG, 64, DIM, SDW, 64, SEG);
    mgemm<2><<<dim3(256,1),256,0,stream>>>(dwbuf, aqpwb+1*16384, aq_bn_g+128, aq_bn_b+128, qh, 128, 2);
    conv_tile<5,true><<<dim3(16,16),256,0,stream>>>(y+256, aq_dw5, dwbuf, 2, SIMG, 64, DIM, SDW, 64, SEG);
    mgemm<2><<<dim3(256,1),256,0,stream>>>(dwbuf, aqpwb+2*16384, aq_bn_g+256, aq_bn_b+256, qh, 128, 4);
    conv_tile<7,true><<<dim3(16,16),256,0,stream>>>(y+384, aq_dw7, dwbuf, 2, SIMG, 64, DIM, SDW, 64, SEG);
    mgemm<2><<<dim3(256,1),256,0,stream>>>(dwbuf, aqpwb+3*16384, aq_bn_g+384, aq_bn_b+384, qh, 128, 6);
    conv_tile<3,true><<<dim3(16,16),256,0,stream>>>(y+512, aq_dw3, dwbuf, 2, SIMG, 64, DIM, SDW, 64, SEG);
    pconv_ln<<<8*NTOK/32,256,0,stream>>>(dwbuf, aq_pw, aq_ln_g, aq_ln_b, qloc);
  }
  const u16* vh = kvh + (size_t)8*NHEADS*NTOK*CH;
  // 4. softmax stats over tokens on k (2-pass)
  softmax_p1<<<dim3(16,64),256,0,stream>>>(kvh, pmb, psb);
  softmax_p2<<<64,64,0,stream>>>(pmb, psb, mbuf, sbuf);
  // 5. kTv = softmax(k)^T v  (per b,h: 64x4096 * 4096x64)
  ktv_partial<<<dim3(16,64),256,0,stream>>>(kvh, vh, mbuf, part);
  ktv_reduce<<<64,256,0,stream>>>(part, sbuf, ktv);
  // 6. CRPE depthwise conv on v (heads 0-1:3x3, 2-4:5x5, 5-7:7x7)
  conv_tile<3,false><<<dim3(16,16),256,0,stream>>>(vh, crpe_w3, cbuf, 2, 8*SHD, SHD, CH, 8*SHD, SHD, CH);
  conv_tile<5,false><<<dim3(16,24),256,0,stream>>>(vh + 2*SHD, crpe_w5, cbuf + 2*SHD, 3, 8*SHD, SHD, CH, 8*SHD, SHD, CH);
  conv_tile<7,false><<<dim3(16,24),256,0,stream>>>(vh + 5*SHD, crpe_w7, cbuf + 5*SHD, 3, 8*SHD, SHD, CH, 8*SHD, SHD, CH);
  // 7. o = SCALE*qh*kTv + qh.*conv(v); concat loc
  oassm_k<<<dim3(64,64),256,0,stream>>>(qh, ktv, cbuf, obuf);
  loccat_k<<<8*NTOK*SEG/256,256,0,stream>>>(kvloc, qloc, obuf);
  // 8. output projection -> fp32 d_out
  mgemm<1><<<dim3(256,5),256,0,stream>>>(obuf, pwb, proj_b, nullptr, (float*)d_out, DIM, 0);
}

// Round 5
// 900.555 us; speedup vs baseline: 4.7055x; 1.0109x over previous
//
#include <hip/hip_runtime.h>
#include <hip/hip_bf16.h>
#include <stdint.h>

#define BATCH 8
#define NTOK 4096
#define DIM 640
#define SEG 128
#define NHEADS 8
#define CH 64
#define SCALE_F 0.11180339887498948f
#define EPS_F 1e-5f
#define BNSCALE 0.99999500003749972f

typedef unsigned short u16;
typedef float f32x4 __attribute__((ext_vector_type(4)));
typedef short bf16x8 __attribute__((ext_vector_type(8)));

__device__ __forceinline__ float b2f(u16 u){
  union { float f; unsigned int i; } c; c.i = ((unsigned int)u)<<16; return c.f;
}
__device__ __forceinline__ u16 f2b(float f){
  union { float f; unsigned int i; } c; c.f = f;
  unsigned int i = c.i;
  return (u16)((i + 0x7fffu + ((i>>16)&1u)) >> 16);
}
__device__ __forceinline__ float hswish(float v){
  return v * fminf(fmaxf(v+3.f,0.f),6.f) * (1.f/6.f);
}
__device__ __forceinline__ int swz(int bx, int n){
  // XCD-bijective swizzle (n divisible by 8)
  return (bx&7)*(n>>3) + (bx>>3);
}

// ---------------- fp32 -> bf16 conversion ----------------
__global__ void cvt_k(const float* __restrict__ in, u16* __restrict__ out, int n){
  int idx = (blockIdx.x*256 + threadIdx.x)*4;
  if (idx>=n) return;
  float4 v = *(const float4*)(in+idx);
  ushort4 o;
  o.x=f2b(v.x); o.y=f2b(v.y); o.z=f2b(v.z); o.w=f2b(v.w);
  *(ushort4*)(out+idx) = o;
}

// merged weight conversion: kv_w, proj_w, aq_pw, akv_pw
__global__ void cvtw_k(const float* __restrict__ w0, const float* __restrict__ w1,
                       const float* __restrict__ w2, const float* __restrict__ w3,
                       u16* __restrict__ o0, u16* __restrict__ o1,
                       u16* __restrict__ o2, u16* __restrict__ o3){
  int i4 = blockIdx.x*256 + threadIdx.x;
  const int n0=819200/4, n1=409600/4, n2=65536/4, n3=65536/4;
  const float* src; u16* dst; int idx;
  if (i4 < n0){ src=w0; dst=o0; idx=i4; }
  else if (i4 < n0+n1){ src=w1; dst=o1; idx=i4-n0; }
  else if (i4 < n0+n1+n2){ src=w2; dst=o2; idx=i4-n0-n1; }
  else if (i4 < n0+n1+n2+n3){ src=w3; dst=o3; idx=i4-n0-n1-n2; }
  else return;
  float4 v = *(const float4*)(src + (size_t)idx*4);
  ushort4 o; o.x=f2b(v.x); o.y=f2b(v.y); o.z=f2b(v.z); o.w=f2b(v.w);
  *(ushort4*)(dst + (size_t)idx*4) = o;
}

// ---------------- MFMA GEMM ----------------
// C[r,o] = sum_k A[r,k]*Wt[o,k]; 128x128 tile, BK=64, 4 waves each 64x64.
// MODE 0: scatter bf16 to kvbuf (2,B,N,DIM) + fused x0 (BN+hswish -> heads 0,1 when o<128).
// MODE 1: +bias -> fp32 (M,640).
// MODE 2: 3 branches via blockIdx.y; BN+hswish -> bf16 head tensor at headbase+2*br.
template<int MODE>
__global__ __launch_bounds__(256)
void mgemm(const u16* __restrict__ A, const u16* __restrict__ Wt,
           const float* __restrict__ e1, const float* __restrict__ e2,
           void* __restrict__ out, int K, int headbase, size_t abr,
           const float* __restrict__ bng, const float* __restrict__ bnb,
           u16* __restrict__ hout)
{
  __shared__ u16 As[128*64];
  __shared__ u16 Bs[128*64];
  int tid = threadIdx.x;
  int wid = tid>>6, lane = tid&63;
  int bx = swz(blockIdx.x, gridDim.x);
  int rb = bx*128, cb;
  if (MODE==2){
    int br = blockIdx.y;
    A  += (size_t)br*abr;
    Wt += (size_t)br*16384;
    e1 += br*128; e2 += br*128;
    headbase += 2*br;
    cb = 0;
  } else {
    cb = blockIdx.y*128;
  }
  int wr = wid>>1, wc = wid&1;
  f32x4 acc[4][4];
  #pragma unroll
  for (int m=0;m<4;m++)
    #pragma unroll
    for (int n=0;n<4;n++) acc[m][n] = (f32x4){0.f,0.f,0.f,0.f};

  const u16* Ab = A + (size_t)rb*K;
  const u16* Bb = Wt + (size_t)cb*K;
  int srow = wid*32 + (lane>>3);
  int scol = (lane&7)*8;

  for (int k0=0;k0<K;k0+=64){
    #pragma unroll
    for (int i=0;i<4;i++){
      const u16* sa = Ab + (size_t)(srow + i*8)*K + k0 + scol;
      const u16* sb = Bb + (size_t)(srow + i*8)*K + k0 + scol;
      u16* la = As + (wid*32 + i*8)*64;
      u16* lb = Bs + (wid*32 + i*8)*64;
      __builtin_amdgcn_global_load_lds((const __attribute__((address_space(1))) void*)sa,
                                       (__attribute__((address_space(3))) void*)la, 16, 0, 0);
      __builtin_amdgcn_global_load_lds((const __attribute__((address_space(1))) void*)sb,
                                       (__attribute__((address_space(3))) void*)lb, 16, 0, 0);
    }
    __syncthreads();
    int fr = lane&15, fk = (lane>>4)*8;
    #pragma unroll
    for (int kk=0;kk<64;kk+=32){
      bf16x8 af[4], bfr[4];
      #pragma unroll
      for (int m=0;m<4;m++) af[m] = *(const bf16x8*)&As[(wr*64 + m*16 + fr)*64 + kk + fk];
      #pragma unroll
      for (int n=0;n<4;n++) bfr[n] = *(const bf16x8*)&Bs[(wc*64 + n*16 + fr)*64 + kk + fk];
      #pragma unroll
      for (int m=0;m<4;m++)
        #pragma unroll
        for (int n=0;n<4;n++)
          acc[m][n] = __builtin_amdgcn_mfma_f32_16x16x32_bf16(af[m], bfr[n], acc[m][n], 0, 0, 0);
    }
    __syncthreads();
  }

  int fr = lane&15, fq = lane>>4;
  #pragma unroll
  for (int m=0;m<4;m++){
    #pragma unroll
    for (int j=0;j<4;j++){
      int r = rb + wr*64 + m*16 + fq*4 + j;
      int bb = r>>12, ntk = r&4095;
      #pragma unroll
      for (int n=0;n<4;n++){
        int o = cb + wc*64 + n*16 + fr;
        float v = acc[m][n][j];
        if (MODE==0){
          int s = (o>=DIM)?1:0; int co = o - s*DIM;
          ((u16*)out)[(((size_t)(s*BATCH+bb))*NTOK + ntk)*DIM + co] = f2b(v);
          if (co < 128){
            float hv = hswish(v*(bng[co]*BNSCALE) + bnb[co]);
            int img = s*BATCH + bb;
            hout[(((size_t)img*NHEADS + (co>>6))*NTOK + ntk)*CH + (co&63)] = f2b(hv);
          }
        } else if (MODE==1){
          ((float*)out)[(size_t)r*DIM + o] = v + e1[o];
        } else {
          float val = hswish(v * (e1[o]*BNSCALE) + e2[o]);
          int head = headbase + (o>>6), c = o&63;
          ((u16*)out)[(((size_t)bb*NHEADS + head)*NTOK + ntk)*CH + c] = f2b(val);
        }
      }
    }
  }
}

// ---------------- tiled depthwise conv (stencil) ----------------
template<int T, bool INF32>
__global__ __launch_bounds__(256)
void conv_tile(const void* __restrict__ in, const float* __restrict__ w,
               u16* __restrict__ out, int NI2,
               size_t S1, size_t S2, int PXS,
               size_t SO1, size_t SO2, int OPXS)
{
  constexpr int P = T>>1;
  constexpr int PW = 15 + T;
  __shared__ u16 lds[PW*PW*64];
  int tid = threadIdx.x;
  int tile = blockIdx.x;
  int ty0 = (tile>>2)*16, tx0 = (tile&3)*16;
  int i = blockIdx.y;
  int i1 = i / NI2, i2 = i - i1*NI2;
  size_t in_off = (size_t)i1*S1 + (size_t)i2*S2;
  size_t out_off = (size_t)i1*SO1 + (size_t)i2*SO2;
  int c = tid & 63;

  float wreg[T*T];
  {
    const float* wp = w + (size_t)(i2*64 + c)*(T*T);
    #pragma unroll
    for (int j=0;j<T*T;j++) wreg[j] = wp[j];
  }

  if constexpr (!INF32){
    int l8 = tid&7;
    for (int p = tid>>3; p < PW*PW; p += 32){
      int py = p/PW, pxx = p - py*PW;
      int gy = ty0+py-P, gx = tx0+pxx-P;
      uint4 val = {0u,0u,0u,0u};
      if ((unsigned)gy<64u && (unsigned)gx<64u)
        val = *(const uint4*)((const u16*)in + in_off + (size_t)(gy*64+gx)*PXS + l8*8);
      *(uint4*)&lds[p*64 + l8*8] = val;
    }
  } else {
    int l16 = tid&15;
    for (int p = tid>>4; p < PW*PW; p += 16){
      int py = p/PW, pxx = p - py*PW;
      int gy = ty0+py-P, gx = tx0+pxx-P;
      ushort4 o4 = {0,0,0,0};
      if ((unsigned)gy<64u && (unsigned)gx<64u){
        float4 v = *(const float4*)((const float*)in + in_off + (size_t)(gy*64+gx)*PXS + l16*4);
        o4.x=f2b(v.x); o4.y=f2b(v.y); o4.z=f2b(v.z); o4.w=f2b(v.w);
      }
      *(ushort4*)&lds[p*64 + l16*4] = o4;
    }
  }
  __syncthreads();

  int ox0 = (tid>>6)*4;
  #pragma unroll 1
  for (int r=0;r<16;r++){
    float a0=0.f,a1=0.f,a2=0.f,a3=0.f;
    #pragma unroll
    for (int dy=0;dy<T;dy++){
      const u16* rowp = &lds[((r+dy)*PW + ox0)*64 + c];
      #pragma unroll
      for (int dxx=0;dxx<T+3;dxx++){
        float v = b2f(rowp[dxx*64]);
        if (dxx<T)             a0 += wreg[dy*T+dxx]*v;
        if (dxx>=1 && dxx<T+1) a1 += wreg[dy*T+dxx-1]*v;
        if (dxx>=2 && dxx<T+2) a2 += wreg[dy*T+dxx-2]*v;
        if (dxx>=3)            a3 += wreg[dy*T+dxx-3]*v;
      }
    }
    size_t ob = out_off + (size_t)((ty0+r)*64 + tx0+ox0)*OPXS + c;
    out[ob]                  = f2b(a0);
    out[ob +   (size_t)OPXS] = f2b(a1);
    out[ob + 2*(size_t)OPXS] = f2b(a2);
    out[ob + 3*(size_t)OPXS] = f2b(a3);
  }
}

// q branch 0: BN+hswish from fp32 y straight into heads 0,1
__global__ void x0_k(const float* __restrict__ in, const float* __restrict__ g,
                     const float* __restrict__ b, u16* __restrict__ hout, int total)
{
  int idx = blockIdx.x*256 + threadIdx.x;
  if (idx>=total) return;
  int c = idx&127; int n = (idx>>7)&4095; int bb = idx>>19;
  float xv = in[((size_t)bb*NTOK+n)*DIM + c];
  float v = hswish(xv * (g[c]*BNSCALE) + b[c]);
  int head = c>>6, ch = c&63;
  hout[(((size_t)bb*NHEADS+head)*NTOK+n)*CH+ch] = f2b(v);
}

// pointwise 128x128 + LayerNorm(128) + hswish; ADD: += kvloc, write into obuf col 512+
template<bool ADD>
__global__ __launch_bounds__(256)
void pconv_ln(const u16* __restrict__ A, const float* __restrict__ W,
              const float* __restrict__ g, const float* __restrict__ bp,
              u16* __restrict__ out, int ostr, int obase,
              const u16* __restrict__ addsrc)
{
  __shared__ float Wc[128][36];
  __shared__ float Ac[32][36];
  int tid = threadIdx.x;
  int r0 = blockIdx.x*32;
  int ty = tid>>5, tx = tid&31;
  float acc[4][4] = {};
  for (int k0=0;k0<128;k0+=32){
    {
      int row = tid>>1, kk = (tid&1)*16;
      const float* wr = W + (size_t)row*128 + k0 + kk;
      float4 a0=*(const float4*)wr, a1=*(const float4*)(wr+4);
      float4 a2=*(const float4*)(wr+8), a3=*(const float4*)(wr+12);
      Wc[row][kk+0]=a0.x; Wc[row][kk+1]=a0.y; Wc[row][kk+2]=a0.z; Wc[row][kk+3]=a0.w;
      Wc[row][kk+4]=a1.x; Wc[row][kk+5]=a1.y; Wc[row][kk+6]=a1.z; Wc[row][kk+7]=a1.w;
      Wc[row][kk+8]=a2.x; Wc[row][kk+9]=a2.y; Wc[row][kk+10]=a2.z; Wc[row][kk+11]=a2.w;
      Wc[row][kk+12]=a3.x; Wc[row][kk+13]=a3.y; Wc[row][kk+14]=a3.z; Wc[row][kk+15]=a3.w;
    }
    {
      int row = tid>>3, kk = (tid&7)*4;
      uint2 p = *(const uint2*)(A + (size_t)(r0+row)*128 + k0 + kk);
      Ac[row][kk+0]=b2f((u16)(p.x&0xffffu)); Ac[row][kk+1]=b2f((u16)(p.x>>16));
      Ac[row][kk+2]=b2f((u16)(p.y&0xffffu)); Ac[row][kk+3]=b2f((u16)(p.y>>16));
    }
    __syncthreads();
    #pragma unroll
    for (int kk=0;kk<32;kk+=4){
      float4 av[4], wv[4];
      #pragma unroll
      for (int i=0;i<4;i++) av[i] = *(const float4*)&Ac[ty*4+i][kk];
      #pragma unroll
      for (int j=0;j<4;j++) wv[j] = *(const float4*)&Wc[tx*4+j][kk];
      #pragma unroll
      for (int i=0;i<4;i++)
        #pragma unroll
        for (int j=0;j<4;j++)
          acc[i][j] += av[i].x*wv[j].x + av[i].y*wv[j].y + av[i].z*wv[j].z + av[i].w*wv[j].w;
    }
    __syncthreads();
  }
  #pragma unroll
  for (int i=0;i<4;i++){
    float s1=0.f,s2=0.f;
    #pragma unroll
    for (int j=0;j<4;j++){ s1+=acc[i][j]; s2+=acc[i][j]*acc[i][j]; }
    for (int m=1;m<32;m<<=1){ s1 += __shfl_xor(s1,m,32); s2 += __shfl_xor(s2,m,32); }
    float mean = s1*(1.f/128.f);
    float var = s2*(1.f/128.f) - mean*mean;
    float rstd = 1.f/sqrtf(var + EPS_F);
    int r = r0 + ty*4 + i; int bb = r>>12; int n = r&4095;
    #pragma unroll
    for (int j=0;j<4;j++){
      int c = tx*4+j;
      float val = hswish((acc[i][j]-mean)*rstd*g[c] + bp[c]);
      if (ADD) val += b2f(addsrc[((size_t)bb*NTOK+n)*SEG + c]);
      out[((size_t)bb*NTOK+n)*ostr + obase + c] = f2b(val);
    }
  }
}

// softmax over tokens: pass1 per-(bh,chunk) max+sumexp, pass2 merge
__global__ __launch_bounds__(256)
void softmax_p1(const u16* __restrict__ kh, float* __restrict__ pm, float* __restrict__ ps)
{
  __shared__ float lm[4][64];
  __shared__ float lsum[4][64];
  int chunk = blockIdx.x, bh = blockIdx.y;
  int tid = threadIdx.x;
  int ch = tid&63, sub = tid>>6;
  const u16* kp = kh + ((size_t)bh*NTOK + chunk*256 + sub*64)*CH + ch;
  float mx = -1e30f;
  for (int t=0;t<64;t++) mx = fmaxf(mx, b2f(kp[(size_t)t*CH]));
  float sm = 0.f;
  for (int t=0;t<64;t++) sm += expf(b2f(kp[(size_t)t*CH]) - mx);
  lm[sub][ch]=mx; lsum[sub][ch]=sm;
  __syncthreads();
  if (sub==0){
    float M = lm[0][ch];
    #pragma unroll
    for (int i=1;i<4;i++) M = fmaxf(M, lm[i][ch]);
    float S = 0.f;
    #pragma unroll
    for (int i=0;i<4;i++) S += lsum[i][ch]*expf(lm[i][ch]-M);
    pm[((size_t)bh*16+chunk)*64+ch]=M;
    ps[((size_t)bh*16+chunk)*64+ch]=S;
  }
}

__global__ void softmax_p2(const float* __restrict__ pm, const float* __restrict__ ps,
                           float* __restrict__ m, float* __restrict__ s)
{
  int bh = blockIdx.x, ch = threadIdx.x;
  float M = -1e30f;
  for (int c=0;c<16;c++) M = fmaxf(M, pm[((size_t)bh*16+c)*64+ch]);
  float S = 0.f;
  for (int c=0;c<16;c++) S += ps[((size_t)bh*16+c)*64+ch]*expf(pm[((size_t)bh*16+c)*64+ch]-M);
  m[bh*CH+ch]=M; s[bh*CH+ch]=S;
}

__global__ __launch_bounds__(256)
void ktv_partial(const u16* __restrict__ kh, const u16* __restrict__ vh,
                 const float* __restrict__ m, float* __restrict__ part)
{
  __shared__ float ek[8][64];
  __shared__ float vv[8][64];
  __shared__ float msh[64];
  int bh = blockIdx.y, chunk = blockIdx.x;
  int tid = threadIdx.x;
  const u16* kp = kh + ((size_t)bh*NTOK + chunk*512)*CH;
  const u16* vp = vh + ((size_t)bh*NTOK + chunk*512)*CH;
  if (tid<64) msh[tid]=m[bh*CH+tid];
  __syncthreads();
  int tkc = tid>>4, tvc = tid&15;
  float acc[4][4]={};
  for (int nn=0;nn<512;nn+=8){
    for (int e=tid;e<512;e+=256){
      int r=e>>6, c=e&63;
      ek[r][c]=expf(b2f(kp[(size_t)(nn+r)*CH+c]) - msh[c]);
      vv[r][c]=b2f(vp[(size_t)(nn+r)*CH+c]);
    }
    __syncthreads();
    #pragma unroll
    for (int i=0;i<8;i++){
      float a[4],b[4];
      #pragma unroll
      for(int u=0;u<4;u++) a[u]=ek[i][tkc*4+u];
      #pragma unroll
      for(int u=0;u<4;u++) b[u]=vv[i][tvc*4+u];
      #pragma unroll
      for(int u=0;u<4;u++)
        #pragma unroll
        for(int w=0;w<4;w++) acc[u][w]+=a[u]*b[w];
    }
    __syncthreads();
  }
  float* pp = part + (((size_t)bh*8 + chunk)*CH*CH);
  #pragma unroll
  for(int u=0;u<4;u++)
    #pragma unroll
    for(int w=0;w<4;w++)
      pp[(tkc*4+u)*CH + tvc*4+w] = acc[u][w];
}

// reduce partials, divide by softmax denom, store TRANSPOSED bf16 (ktvT[vc][kc])
__global__ void ktv_reduce(const float* __restrict__ part, const float* __restrict__ s,
                           u16* __restrict__ ktvT)
{
  int bh = blockIdx.x; int tid = threadIdx.x;
  for (int o=tid;o<CH*CH;o+=256){
    float sum=0.f;
    for (int c=0;c<8;c++) sum += part[(((size_t)bh*8+c)*CH*CH)+o];
    int kc = o>>6, vc = o&63;
    ktvT[(size_t)bh*CH*CH + vc*CH + kc] = f2b(sum / s[bh*CH + kc]);
  }
}

// eff = qh @ ktv (M=128/block, K=64, N=64) + fused  SCALE*eff + qh.*cbuf  -> obuf
__global__ __launch_bounds__(256)
void oeff_k(const u16* __restrict__ qh, const u16* __restrict__ ktvT,
            const u16* __restrict__ cbuf, u16* __restrict__ obuf)
{
  __shared__ u16 qs[128*64];
  __shared__ u16 kt[64*64];
  int tid = threadIdx.x;
  int wid = tid>>6, lane = tid&63;
  int bx = swz(blockIdx.x, gridDim.x);
  int bh = blockIdx.y; int b = bh>>3, h = bh&7;
  int n0 = bx*128;
  const u16* qp = qh + ((size_t)bh*NTOK + n0)*CH;
  const u16* kp = ktvT + (size_t)bh*CH*CH;
  int srow = lane>>3, scol = (lane&7)*8;
  #pragma unroll
  for (int i=0;i<4;i++){
    const u16* sa = qp + (size_t)(wid*32 + i*8 + srow)*CH + scol;
    u16* la = qs + (wid*32 + i*8)*64;
    __builtin_amdgcn_global_load_lds((const __attribute__((address_space(1))) void*)sa,
                                     (__attribute__((address_space(3))) void*)la, 16, 0, 0);
  }
  #pragma unroll
  for (int i=0;i<2;i++){
    const u16* sb = kp + (size_t)(wid*16 + i*8 + srow)*CH + scol;
    u16* lb = kt + (wid*16 + i*8)*64;
    __builtin_amdgcn_global_load_lds((const __attribute__((address_space(1))) void*)sb,
                                     (__attribute__((address_space(3))) void*)lb, 16, 0, 0);
  }
  __syncthreads();

  int fr = lane&15, fk = (lane>>4)*8;
  f32x4 acc[2][4];
  #pragma unroll
  for (int m=0;m<2;m++)
    #pragma unroll
    for (int n=0;n<4;n++) acc[m][n] = (f32x4){0.f,0.f,0.f,0.f};
  #pragma unroll
  for (int kk=0;kk<64;kk+=32){
    bf16x8 af[2], bfr[4];
    #pragma unroll
    for (int m=0;m<2;m++) af[m] = *(const bf16x8*)&qs[(wid*32 + m*16 + fr)*64 + kk + fk];
    #pragma unroll
    for (int n=0;n<4;n++) bfr[n] = *(const bf16x8*)&kt[(n*16 + fr)*64 + kk + fk];
    #pragma unroll
    for (int m=0;m<2;m++)
      #pragma unroll
      for (int n=0;n<4;n++)
        acc[m][n] = __builtin_amdgcn_mfma_f32_16x16x32_bf16(af[m], bfr[n], acc[m][n], 0, 0, 0);
  }

  int fq = lane>>4;
  #pragma unroll
  for (int m=0;m<2;m++){
    #pragma unroll
    for (int j=0;j<4;j++){
      int rl = wid*32 + m*16 + fq*4 + j;
      int tok = n0 + rl;
      const u16* cp = cbuf + ((size_t)bh*NTOK + tok)*CH;
      u16* op = obuf + ((size_t)b*NTOK + tok)*DIM + h*CH;
      #pragma unroll
      for (int n=0;n<4;n++){
        int col = n*16 + fr;
        float val = SCALE_F*acc[m][n][j] + b2f(qs[rl*64 + col])*b2f(cp[col]);
        op[col] = f2b(val);
      }
    }
  }
}

extern "C" void kernel_launch(void* const* d_in, const int* in_sizes, int n_in,
                              void* d_out, int out_size, void* d_ws, size_t ws_size,
                              hipStream_t stream)
{
  const float* x = (const float*)d_in[0];
  const float* y = (const float*)d_in[1];
  const float* kv_w = (const float*)d_in[2];
  const float* proj_w = (const float*)d_in[3];
  const float* proj_b = (const float*)d_in[4];
  const float* crpe_w3 = (const float*)d_in[5];
  const float* crpe_w5 = (const float*)d_in[6];
  const float* crpe_w7 = (const float*)d_in[7];
  const float* aq_dw3 = (const float*)d_in[8];
  const float* aq_dw5 = (const float*)d_in[9];
  const float* aq_dw7 = (const float*)d_in[10];
  const float* aq_pw  = (const float*)d_in[11];
  const float* aq_ln_g = (const float*)d_in[12];
  const float* aq_ln_b = (const float*)d_in[13];
  const float* aq_bn_g = (const float*)d_in[14];
  const float* aq_bn_b = (const float*)d_in[15];
  const float* akv_dw3 = (const float*)d_in[16];
  const float* akv_dw5 = (const float*)d_in[17];
  const float* akv_dw7 = (const float*)d_in[18];
  const float* akv_pw  = (const float*)d_in[19];
  const float* akv_ln_g = (const float*)d_in[20];
  const float* akv_ln_b = (const float*)d_in[21];
  const float* akv_bn_g = (const float*)d_in[22];
  const float* akv_bn_b = (const float*)d_in[23];

  const size_t SIMG = (size_t)NTOK*DIM;
  const size_t SDW  = (size_t)NTOK*SEG;
  const size_t SHD  = (size_t)NTOK*CH;

  char* ws = (char*)d_ws;
  size_t off=0;
  auto alloc=[&](size_t bytes)->char*{ char* p = ws+off; off=(off+bytes+255)&~(size_t)255; return p; };
  u16* kvbuf = (u16*)alloc((size_t)16*SIMG*2);
  u16* kvh   = (u16*)alloc((size_t)16*NHEADS*SHD*2);
  u16* qh    = (u16*)alloc((size_t)8*NHEADS*SHD*2);
  char* dwbR = alloc((size_t)3*16*SDW*2);          // 3 branch dwconv buffers (50.3MB)
  u16* dwb0  = (u16*)dwbR;
  u16* dwb1  = dwb0 + (size_t)16*SDW;
  u16* dwb2  = dwb1 + (size_t)16*SDW;
  // part/ktvT/cbuf overlap dwbR (dead after aggregators)
  float* part = (float*)dwbR;                      // 8.39MB
  u16* ktvT  = (u16*)(dwbR + 8*1024*1024 + 512*1024);   // 0.52MB
  u16* cbuf  = (u16*)(dwbR + 10*1024*1024);             // 33.5MB (total 43.5 <= 50.3)
  u16* kvloc = (u16*)alloc((size_t)8*SDW*2);
  float* mbuf = (float*)alloc((size_t)64*64*4);
  float* sbuf = (float*)alloc((size_t)64*64*4);
  float* pmb  = (float*)alloc((size_t)64*16*64*4);
  float* psb  = (float*)alloc((size_t)64*16*64*4);
  u16* xb    = (u16*)alloc((size_t)BATCH*SIMG*2);
  u16* kvwb  = (u16*)alloc((size_t)2*DIM*DIM*2);
  u16* pwb   = (u16*)alloc((size_t)DIM*DIM*2);
  u16* aqpwb = (u16*)alloc((size_t)4*SEG*SEG*2);
  u16* akvpwb= (u16*)alloc((size_t)4*SEG*SEG*2);
  u16* obuf  = kvbuf;

  // 0. fp32 -> bf16 conversions
  {
    int nx = BATCH*NTOK*DIM;
    cvt_k<<<(nx/4+255)/256,256,0,stream>>>(x, xb, nx);
    cvtw_k<<<1329,256,0,stream>>>(kv_w, proj_w, aq_pw, akv_pw, kvwb, pwb, aqpwb, akvpwb);
  }

  // 1. kv projection GEMM + fused x0(kv) epilogue
  mgemm<0><<<dim3(256,10),256,0,stream>>>(xb, kvwb, nullptr, nullptr, kvbuf, DIM, 0, 0,
                                          akv_bn_g, akv_bn_b, kvh);

  // 2. kv aggregator (B_=16)
  {
    conv_tile<3,false><<<dim3(16,32),256,0,stream>>>(kvbuf+128, akv_dw3+1152, dwb0, 2, SIMG, 64, DIM, SDW, 64, SEG);
    conv_tile<5,false><<<dim3(16,32),256,0,stream>>>(kvbuf+256, akv_dw5,      dwb1, 2, SIMG, 64, DIM, SDW, 64, SEG);
    conv_tile<7,false><<<dim3(16,32),256,0,stream>>>(kvbuf+384, akv_dw7,      dwb2, 2, SIMG, 64, DIM, SDW, 64, SEG);
    mgemm<2><<<dim3(512,3),256,0,stream>>>(dwb0, akvpwb+16384, akv_bn_g+128, akv_bn_b+128, kvh, 128, 2,
                                           (size_t)16*SDW, nullptr, nullptr, nullptr);
    conv_tile<3,false><<<dim3(16,16),256,0,stream>>>(kvbuf + (size_t)8*SIMG + 512, akv_dw3, dwb0, 2, SIMG, 64, DIM, SDW, 64, SEG);
    pconv_ln<false><<<8*NTOK/32,256,0,stream>>>(dwb0, akv_pw, akv_ln_g, akv_ln_b, kvloc, SEG, 0, nullptr);
  }
  // 3. q aggregator (B_=8)
  {
    int tot = 8*NTOK*SEG;
    x0_k<<<tot/256,256,0,stream>>>(y, aq_bn_g, aq_bn_b, qh, tot);
    conv_tile<3,true><<<dim3(16,16),256,0,stream>>>(y+128, aq_dw3+1152, dwb0, 2, SIMG, 64, DIM, SDW, 64, SEG);
    conv_tile<5,true><<<dim3(16,16),256,0,stream>>>(y+256, aq_dw5,      dwb1, 2, SIMG, 64, DIM, SDW, 64, SEG);
    conv_tile<7,true><<<dim3(16,16),256,0,stream>>>(y+384, aq_dw7,      dwb2, 2, SIMG, 64, DIM, SDW, 64, SEG);
    mgemm<2><<<dim3(256,3),256,0,stream>>>(dwb0, aqpwb+16384, aq_bn_g+128, aq_bn_b+128, qh, 128, 2,
                                           (size_t)16*SDW, nullptr, nullptr, nullptr);
    conv_tile<3,true><<<dim3(16,16),256,0,stream>>>(y+512, aq_dw3, dwb0, 2, SIMG, 64, DIM, SDW, 64, SEG);
    pconv_ln<true><<<8*NTOK/32,256,0,stream>>>(dwb0, aq_pw, aq_ln_g, aq_ln_b, obuf, DIM, 512, kvloc);
  }
  const u16* vh = kvh + (size_t)8*NHEADS*SHD;
  // 4. softmax stats (2-pass)
  softmax_p1<<<dim3(16,64),256,0,stream>>>(kvh, pmb, psb);
  softmax_p2<<<64,64,0,stream>>>(pmb, psb, mbuf, sbuf);
  // 5. kTv
  ktv_partial<<<dim3(8,64),256,0,stream>>>(kvh, vh, mbuf, part);
  ktv_reduce<<<64,256,0,stream>>>(part, sbuf, ktvT);
  // 6. CRPE depthwise conv on v
  conv_tile<3,false><<<dim3(16,16),256,0,stream>>>(vh,         crpe_w3, cbuf,         2, 8*SHD, SHD, CH, 8*SHD, SHD, CH);
  conv_tile<5,false><<<dim3(16,24),256,0,stream>>>(vh + 2*SHD, crpe_w5, cbuf + 2*SHD, 3, 8*SHD, SHD, CH, 8*SHD, SHD, CH);
  conv_tile<7,false><<<dim3(16,24),256,0,stream>>>(vh + 5*SHD, crpe_w7, cbuf + 5*SHD, 3, 8*SHD, SHD, CH, 8*SHD, SHD, CH);
  // 7. o = SCALE*qh*kTv + qh.*conv(v)  (MFMA, fused epilogue)
  oeff_k<<<dim3(32,64),256,0,stream>>>(qh, ktvT, cbuf, obuf);
  // 8. output projection -> fp32 d_out
  mgemm<1><<<dim3(256,5),256,0,stream>>>(obuf, pwb, proj_b, nullptr, (float*)d_out, DIM, 0, 0,
                                         nullptr, nullptr, nullptr);
}